// Round 3
// baseline (429.828 us; speedup 1.0000x reference)
//
#include <hip/hip_runtime.h>
#include <hip/hip_bf16.h>
#include <math.h>

#define D_MODEL 1024
#define ATT 1024
#define NHEAD 16
#define HDIM 64
#define BATCH 2
#define SEQ 2048
#define M_ROWS (BATCH * SEQ) /* 4096 */

typedef unsigned short u16;
typedef unsigned int u32;
typedef __bf16 bf16x8 __attribute__((ext_vector_type(8)));
typedef float f4 __attribute__((ext_vector_type(4)));
typedef u16 u16x8 __attribute__((ext_vector_type(8)));
typedef u16 u16x4 __attribute__((ext_vector_type(4)));

static_assert(sizeof(u16x8) == 16, "u16x8 must be 16B");

// ---------- bf16 split helpers ----------
__device__ __forceinline__ u16 f32_to_bf16(float f) {
    union { float f; unsigned u; } c; c.f = f;
    unsigned u = c.u;
    return (u16)((u + 0x7FFFu + ((u >> 16) & 1u)) >> 16);  // RNE
}
__device__ __forceinline__ float bf16_to_f32(u16 h) {
    union { unsigned u; float f; } c; c.u = ((unsigned)h) << 16;
    return c.f;
}
__device__ __forceinline__ void split2(float f, u16& hi, u16& lo) {
    hi = f32_to_bf16(f);
    lo = f32_to_bf16(f - bf16_to_f32(hi));
}

__device__ __forceinline__ f4 mfma16(u16x8 a, u16x8 b, f4 c) {
    union U { u16x8 u; bf16x8 b; };
    U ua, ub; ua.u = a; ub.u = b;
    return __builtin_amdgcn_mfma_f32_16x16x32_bf16(ua.b, ub.b, c, 0, 0, 0);
}

// async global->LDS, 16B per lane, dest = uniform base + lane*16
__device__ __forceinline__ void gload16(const void* g, void* l) {
    __builtin_amdgcn_global_load_lds(
        (const __attribute__((address_space(1))) void*)g,
        (__attribute__((address_space(3))) void*)l, 16, 0, 0);
}

// ---------- kernel 1: elementwise split of x ----------
__global__ __launch_bounds__(256) void k_split(const float* __restrict__ in,
                                               u16* __restrict__ hi,
                                               u16* __restrict__ lo, int n4) {
    int i = blockIdx.x * blockDim.x + threadIdx.x;
    if (i >= n4) return;
    const float4 v = ((const float4*)in)[i];
    float vv[4] = {v.x, v.y, v.z, v.w};
    u16 hh[4], ll[4];
#pragma unroll
    for (int j = 0; j < 4; ++j) split2(vv[j], hh[j], ll[j]);
    u16x4 hv = {hh[0], hh[1], hh[2], hh[3]};
    u16x4 lv = {ll[0], ll[1], ll[2], ll[3]};
    *(u16x4*)(hi + (size_t)i * 4) = hv;
    *(u16x4*)(lo + (size_t)i * 4) = lv;
}

// ---------- kernel 2: split + transpose a 1024x1024 weight ----------
__global__ __launch_bounds__(256) void k_splitT(const float* __restrict__ W,
                                                u16* __restrict__ hiT,
                                                u16* __restrict__ loT) {
    __shared__ float tile[32][33];
    int n0 = blockIdx.x * 32, k0 = blockIdx.y * 32;
    int tx = threadIdx.x, ty = threadIdx.y;  // (32,8)
#pragma unroll
    for (int j = 0; j < 4; ++j) {
        int r = ty + j * 8;
        tile[r][tx] = W[(size_t)(k0 + r) * ATT + n0 + tx];
    }
    __syncthreads();
#pragma unroll
    for (int j = 0; j < 4; ++j) {
        int r = ty + j * 8;              // local n
        float v = tile[tx][r];           // = W[k0+tx][n0+r]
        u16 h, l; split2(v, h, l);
        hiT[(size_t)(n0 + r) * D_MODEL + k0 + tx] = h;
        loT[(size_t)(n0 + r) * D_MODEL + k0 + tx] = l;
    }
}

// ---------- kernel 2b: u16 tiled transpose (for V^T), z selects hi/lo ----------
__global__ __launch_bounds__(256) void k_transpose(
    const u16* __restrict__ src_h, const u16* __restrict__ src_l,
    u16* __restrict__ dst_h, u16* __restrict__ dst_l, int srcld, int dstld) {
    __shared__ u16 t[64][72];
    const u16* src = blockIdx.z ? src_l : src_h;
    u16* dst = blockIdx.z ? dst_l : dst_h;
    int n0 = blockIdx.x * 64, m0 = blockIdx.y * 64;
    int tid = threadIdx.x;
    int r = tid >> 2, c16 = (tid & 3) * 16;
    *(u16x8*)&t[r][c16]     = *(const u16x8*)&src[(size_t)(m0 + r) * srcld + n0 + c16];
    *(u16x8*)&t[r][c16 + 8] = *(const u16x8*)&src[(size_t)(m0 + r) * srcld + n0 + c16 + 8];
    __syncthreads();
    u16x8 o0, o1;
#pragma unroll
    for (int j = 0; j < 8; ++j) { o0[j] = t[c16 + j][r]; o1[j] = t[c16 + 8 + j][r]; }
    *(u16x8*)&dst[(size_t)(n0 + r) * dstld + m0 + c16]     = o0;
    *(u16x8*)&dst[(size_t)(n0 + r) * dstld + m0 + c16 + 8] = o1;
}

// ---------- kernel 3: split-bf16 GEMM via global_load_lds + XOR swizzle ----------
// C[M][N] = A[M][K] * B^T[N][K] + bias.  BM = MF*32, BN = 128, BK = 32.
template <int MF, int SPLIT_OUT>
__global__ __launch_bounds__(256) void k_gemm(
    const u16* __restrict__ Ah, const u16* __restrict__ Al,
    const u16* __restrict__ Bh, const u16* __restrict__ Bl,
    const float* __restrict__ bq, const float* __restrict__ bk,
    const float* __restrict__ bv,
    float* __restrict__ Co, u16* __restrict__ Ch, u16* __restrict__ Cl,
    int M, int N, int K, int NBX) {
    constexpr int BM = MF * 32;
    constexpr int SAe = BM * 32;               // elems per A buffer
    constexpr int NCH = (2 * BM + 256) / 16;   // 1KB chunks per K-step
    constexpr int CPW = NCH / 4;
    __shared__ u16 sh[(2 * BM + 256) * 32];

    int tid = threadIdx.x;
    int wave = tid >> 6, lane = tid & 63, lg = lane >> 4, ln = lane & 15;
    int wm = wave >> 1, wn = wave & 1;

    int nb = gridDim.x;
    int bs = (blockIdx.x & 7) * (nb >> 3) + (blockIdx.x >> 3);  // XCD-chunked
    int bx = bs % NBX, by = bs / NBX;
    int m0 = by * BM, n0 = bx * 128;

    f4 acc[MF][4];
#pragma unroll
    for (int i = 0; i < MF; ++i)
#pragma unroll
        for (int j = 0; j < 4; ++j) acc[i][j] = f4{0.f, 0.f, 0.f, 0.f};

    for (int kk = 0; kk < K; kk += 32) {
#pragma unroll
        for (int j = 0; j < CPW; ++j) {
            int c = wave * CPW + j;
            int bo = c << 10;  // byte offset into sh (wave-uniform)
            const u16* base; int local, r0;
            if (bo < BM * 64)                { base = Ah; local = bo;                 r0 = m0; }
            else if (bo < 2 * BM * 64)       { base = Al; local = bo - BM * 64;       r0 = m0; }
            else if (bo < 2 * BM * 64 + 8192){ base = Bh; local = bo - 2 * BM * 64;   r0 = n0; }
            else                             { base = Bl; local = bo - 2 * BM * 64 - 8192; r0 = n0; }
            int lo2 = local + lane * 16;
            int row = lo2 >> 6;
            int cb  = (lo2 >> 4) & 3;
            int cbs = cb ^ ((row >> 1) & 3);      // inverse-swizzled SOURCE
            gload16(base + (size_t)(r0 + row) * K + kk + cbs * 8, (char*)sh + bo);
        }
        __syncthreads();

        u16x8 a_h[MF], a_l[MF], b_h[4], b_l[4];
#pragma unroll
        for (int mf = 0; mf < MF; ++mf) {
            int row = wm * (MF * 16) + mf * 16 + ln;
            int off = row * 32 + ((lg ^ ((row >> 1) & 3)) << 3);  // swizzled READ
            a_h[mf] = *(const u16x8*)&sh[off];
            a_l[mf] = *(const u16x8*)&sh[SAe + off];
        }
#pragma unroll
        for (int nf = 0; nf < 4; ++nf) {
            int row = wn * 64 + nf * 16 + ln;
            int off = row * 32 + ((lg ^ ((row >> 1) & 3)) << 3);
            b_h[nf] = *(const u16x8*)&sh[2 * SAe + off];
            b_l[nf] = *(const u16x8*)&sh[2 * SAe + 4096 + off];
        }
#pragma unroll
        for (int mf = 0; mf < MF; ++mf)
#pragma unroll
            for (int nf = 0; nf < 4; ++nf) {
                acc[mf][nf] = mfma16(a_h[mf], b_h[nf], acc[mf][nf]);
                acc[mf][nf] = mfma16(a_h[mf], b_l[nf], acc[mf][nf]);
                acc[mf][nf] = mfma16(a_l[mf], b_h[nf], acc[mf][nf]);
            }
        __syncthreads();
    }

#pragma unroll
    for (int mf = 0; mf < MF; ++mf)
#pragma unroll
        for (int nf = 0; nf < 4; ++nf) {
            int col = n0 + wn * 64 + nf * 16 + ln;
            float bb;
            if (bk) bb = col < 1024 ? bq[col] : (col < 2048 ? bk[col - 1024] : bv[col - 2048]);
            else    bb = bq[col];
#pragma unroll
            for (int r = 0; r < 4; ++r) {
                int row = m0 + wm * (MF * 16) + mf * 16 + lg * 4 + r;
                float v = acc[mf][nf][r] + bb;
                if (SPLIT_OUT) {
                    u16 h, l; split2(v, h, l);
                    Ch[(size_t)row * N + col] = h;
                    Cl[(size_t)row * N + col] = l;
                } else {
                    Co[(size_t)row * N + col] = v;
                }
            }
        }
}

// ---------- kernel 4: flash attention, QBLK=64, denominator via ones-MFMA ----------
// Q/K from fused qkv [M][3072]; V pre-transposed vt [ATT][M_ROWS].
// LDS (u16 elems): Kh[0,4096) Kl[4096) Vh[8192) Vl[12288) P[16384,20480) = 40KB
// 128B rows for K/V, swizzle kb' = kb ^ (row&7); P rows 64 keys, same swizzle.
__global__ __launch_bounds__(256) void k_attn(
    const u16* __restrict__ qkv_h, const u16* __restrict__ qkv_l,
    const u16* __restrict__ vt_h, const u16* __restrict__ vt_l,
    u16* __restrict__ Oh, u16* __restrict__ Ol) {
    __shared__ u16 sh[20480];
    int tid = threadIdx.x;
    int w = tid >> 6, lane = tid & 63, lg = lane >> 4, ln = lane & 15;

    int bs = (blockIdx.x & 7) * 128 + (blockIdx.x >> 3);  // XCD-chunked, 1024 blocks
    int qt = bs & 31, h = (bs >> 5) & 15, b = bs >> 9;
    int q0 = qt * 64;

    // Q fragments in registers (wave owns q-rows q0 + w*16 .. +15)
    u16x8 qh[2], ql[2];
    {
        int row = q0 + w * 16 + ln;
        const u16* ph_ = qkv_h + (size_t)(b * SEQ + row) * 3072 + h * HDIM;
        const u16* pl_ = qkv_l + (size_t)(b * SEQ + row) * 3072 + h * HDIM;
#pragma unroll
        for (int ks = 0; ks < 2; ++ks) {
            qh[ks] = *(const u16x8*)(ph_ + ks * 32 + lg * 8);
            ql[ks] = *(const u16x8*)(pl_ + ks * 32 + lg * 8);
        }
    }

    f4 acco[4];           // O accumulator, cols nf*16+ln
    f4 accl;              // denominator accumulator (P @ ones)
#pragma unroll
    for (int j = 0; j < 4; ++j) acco[j] = f4{0.f, 0.f, 0.f, 0.f};
    accl = f4{0.f, 0.f, 0.f, 0.f};
    float run_m[4];
#pragma unroll
    for (int r = 0; r < 4; ++r) run_m[r] = -INFINITY;

    u16x8 ones;
#pragma unroll
    for (int j = 0; j < 8; ++j) ones[j] = 0x3F80;  // bf16 1.0

    const u16* Kh_base = qkv_h + (size_t)(b * SEQ) * 3072 + 1024 + h * HDIM;
    const u16* Kl_base = qkv_l + (size_t)(b * SEQ) * 3072 + 1024 + h * HDIM;
    const u16* Vh_base = vt_h + (size_t)(h * HDIM) * M_ROWS + b * SEQ;
    const u16* Vl_base = vt_l + (size_t)(h * HDIM) * M_ROWS + b * SEQ;

    for (int kk = 0; kk < SEQ; kk += 64) {
        // stage K hi/lo + V^T hi/lo, 8KB each, via global_load_lds
#pragma unroll
        for (int j = 0; j < 8; ++j) {
            int c = w * 8 + j;
            int bo = c << 10;
            int buf = bo >> 13;
            int local = bo & 8191;
            int lo2 = local + lane * 16;
            int row = lo2 >> 7;       // 0..63
            int kb  = (lo2 >> 4) & 7;
            int kbs = kb ^ (row & 7); // inverse-swizzled source
            const u16* g;
            if (buf == 0)      g = Kh_base + (size_t)(kk + row) * 3072 + kbs * 8;
            else if (buf == 1) g = Kl_base + (size_t)(kk + row) * 3072 + kbs * 8;
            else if (buf == 2) g = Vh_base + (size_t)row * M_ROWS + kk + kbs * 8;
            else               g = Vl_base + (size_t)row * M_ROWS + kk + kbs * 8;
            gload16(g, (char*)sh + bo);
        }
        __syncthreads();

        // ---- S = Q K^T / 8 ----
        f4 s[4];
#pragma unroll
        for (int j = 0; j < 4; ++j) s[j] = f4{0.f, 0.f, 0.f, 0.f};
#pragma unroll
        for (int nf = 0; nf < 4; ++nf) {
            int krow = nf * 16 + ln;
#pragma unroll
            for (int ks = 0; ks < 2; ++ks) {
                int off = krow * 64 + (((4 * ks + lg) ^ (krow & 7)) << 3);
                u16x8 bh = *(const u16x8*)&sh[off];
                u16x8 bl = *(const u16x8*)&sh[4096 + off];
                s[nf] = mfma16(qh[ks], bh, s[nf]);
                s[nf] = mfma16(qh[ks], bl, s[nf]);
                s[nf] = mfma16(ql[ks], bh, s[nf]);
            }
        }
#pragma unroll
        for (int j = 0; j < 4; ++j) s[j] = s[j] * 0.125f;

        // ---- online softmax: max-reduce only; P (bf16) to LDS; rescale O,l ----
#pragma unroll
        for (int r = 0; r < 4; ++r) {
            float mx = fmaxf(fmaxf(s[0][r], s[1][r]), fmaxf(s[2][r], s[3][r]));
#pragma unroll
            for (int d = 1; d < 16; d <<= 1) mx = fmaxf(mx, __shfl_xor(mx, d));
            float nm = fmaxf(run_m[r], mx);
            float corr = __expf(run_m[r] - nm);
            run_m[r] = nm;
            int qrow = w * 16 + lg * 4 + r;
            int swz = qrow & 7;
            int pbase = 16384 + qrow * 64 + (ln & 7);
#pragma unroll
            for (int nf = 0; nf < 4; ++nf) {
                float p = __expf(s[nf][r] - nm);
                u16 ph = f32_to_bf16(p);
                sh[pbase + (((nf * 2 + (ln >> 3)) ^ swz) << 3)] = ph;
            }
#pragma unroll
            for (int nf = 0; nf < 4; ++nf) acco[nf][r] *= corr;
            accl[r] *= corr;
        }
        // P is wave-private (written & read by same wave) -> no barrier needed

        // ---- O += P V ; l += P @ 1 ----
#pragma unroll
        for (int ks = 0; ks < 2; ++ks) {
            int prow = w * 16 + ln;
            u16x8 pa = *(const u16x8*)&sh[16384 + prow * 64 + (((4 * ks + lg) ^ (prow & 7)) << 3)];
#pragma unroll
            for (int nf = 0; nf < 4; ++nf) {
                int vrow = nf * 16 + ln;
                int off = vrow * 64 + (((4 * ks + lg) ^ (vrow & 7)) << 3);
                u16x8 vh = *(const u16x8*)&sh[8192 + off];
                u16x8 vl = *(const u16x8*)&sh[12288 + off];
                acco[nf] = mfma16(pa, vh, acco[nf]);
                acco[nf] = mfma16(pa, vl, acco[nf]);
            }
            accl = mfma16(pa, ones, accl);
        }
        __syncthreads();
    }

    // ---- epilogue: O /= l (every lane holds l), split-write ----
#pragma unroll
    for (int nf = 0; nf < 4; ++nf) {
        int col = h * HDIM + nf * 16 + ln;
#pragma unroll
        for (int r = 0; r < 4; ++r) {
            int row = q0 + w * 16 + lg * 4 + r;
            float v = acco[nf][r] / accl[r];
            u16 hh, ll; split2(v, hh, ll);
            Oh[(size_t)(b * SEQ + row) * ATT + col] = hh;
            Ol[(size_t)(b * SEQ + row) * ATT + col] = ll;
        }
    }
}

// ---------- launcher ----------
extern "C" void kernel_launch(void* const* d_in, const int* in_sizes, int n_in,
                              void* d_out, int out_size, void* d_ws, size_t ws_size,
                              hipStream_t stream) {
    const float* x  = (const float*)d_in[0];
    const float* Wq = (const float*)d_in[1];
    const float* bq = (const float*)d_in[2];
    const float* Wk = (const float*)d_in[3];
    const float* bk = (const float*)d_in[4];
    const float* Wv = (const float*)d_in[5];
    const float* bv = (const float*)d_in[6];
    const float* Wo = (const float*)d_in[7];
    const float* bo = (const float*)d_in[8];
    float* out = (float*)d_out;

    const size_t MK = (size_t)M_ROWS * ATT;   // 4M elems
    const size_t WE = (size_t)D_MODEL * ATT;  // 1M elems
    const size_t M3 = (size_t)M_ROWS * 3072;  // fused qkv elems

    char* p = (char*)d_ws;
    auto alloc = [&](size_t bytes) -> u16* {
        u16* r = (u16*)p;
        p += (bytes + 255) & ~(size_t)255;
        return r;
    };
    u16* x_hi  = alloc(MK * 2); u16* x_lo  = alloc(MK * 2);
    u16* wT_h  = alloc(3 * WE * 2); u16* wT_l  = alloc(3 * WE * 2);  // [Wq;Wk;Wv]^T stacked
    u16* woT_h = alloc(WE * 2); u16* woT_l = alloc(WE * 2);
    u16* qkv_h = alloc(M3 * 2); u16* qkv_l = alloc(M3 * 2);          // [M][3072]
    u16* vt_h  = alloc(MK * 2); u16* vt_l  = alloc(MK * 2);          // V^T [1024][4096]
    u16* at_h = x_hi; u16* at_l = x_lo;  // attention out reuses x buffers

    k_split<<<dim3((unsigned)(MK / 4 / 256)), 256, 0, stream>>>(x, x_hi, x_lo, (int)(MK / 4));

    dim3 bt(32, 8), gt(32, 32);
    k_splitT<<<gt, bt, 0, stream>>>(Wq, wT_h, wT_l);
    k_splitT<<<gt, bt, 0, stream>>>(Wk, wT_h + WE, wT_l + WE);
    k_splitT<<<gt, bt, 0, stream>>>(Wv, wT_h + 2 * WE, wT_l + 2 * WE);
    k_splitT<<<gt, bt, 0, stream>>>(Wo, woT_h, woT_l);

    // fused QKV: [4096 x 3072] = x[4096x1024] @ [Wq|Wk|Wv], 768 blocks (3/CU)
    k_gemm<4, 1><<<768, 256, 0, stream>>>(x_hi, x_lo, wT_h, wT_l, bq, bk, bv,
                                          nullptr, qkv_h, qkv_l, M_ROWS, 3072, 1024, 24);

    // V^T: qkv cols [2048,3072) -> vt [1024][4096]
    k_transpose<<<dim3(16, 64, 2), 256, 0, stream>>>(qkv_h + 2048, qkv_l + 2048,
                                                     vt_h, vt_l, 3072, M_ROWS);

    // attention: 1024 blocks (4/CU), QBLK=64
    k_attn<<<1024, 256, 0, stream>>>(qkv_h, qkv_l, vt_h, vt_l, at_h, at_l);

    // Wo: BM=64 -> 512 blocks (2/CU)
    k_gemm<2, 0><<<512, 256, 0, stream>>>(at_h, at_l, woT_h, woT_l, bo, nullptr, nullptr,
                                          out, nullptr, nullptr, M_ROWS, 1024, 1024, 8);
}

// Round 4
// 370.657 us; speedup vs baseline: 1.1596x; 1.1596x over previous
//
#include <hip/hip_runtime.h>
#include <hip/hip_bf16.h>
#include <math.h>

#define D_MODEL 1024
#define ATT 1024
#define NHEAD 16
#define HDIM 64
#define BATCH 2
#define SEQ 2048
#define M_ROWS (BATCH * SEQ) /* 4096 */

typedef unsigned short u16;
typedef unsigned int u32;
typedef __bf16 bf16x8 __attribute__((ext_vector_type(8)));
typedef float f4 __attribute__((ext_vector_type(4)));
typedef u16 u16x8 __attribute__((ext_vector_type(8)));
typedef u16 u16x4 __attribute__((ext_vector_type(4)));

static_assert(sizeof(u16x8) == 16, "u16x8 must be 16B");

// ---------- bf16 split helpers ----------
__device__ __forceinline__ u16 f32_to_bf16(float f) {
    union { float f; unsigned u; } c; c.f = f;
    unsigned u = c.u;
    return (u16)((u + 0x7FFFu + ((u >> 16) & 1u)) >> 16);  // RNE
}
__device__ __forceinline__ float bf16_to_f32(u16 h) {
    union { unsigned u; float f; } c; c.u = ((unsigned)h) << 16;
    return c.f;
}
__device__ __forceinline__ void split2(float f, u16& hi, u16& lo) {
    hi = f32_to_bf16(f);
    lo = f32_to_bf16(f - bf16_to_f32(hi));
}

__device__ __forceinline__ f4 mfma16(u16x8 a, u16x8 b, f4 c) {
    union U { u16x8 u; bf16x8 b; };
    U ua, ub; ua.u = a; ub.u = b;
    return __builtin_amdgcn_mfma_f32_16x16x32_bf16(ua.b, ub.b, c, 0, 0, 0);
}

// async global->LDS, 16B per lane, dest = uniform base + lane*16
__device__ __forceinline__ void gload16(const void* g, void* l) {
    __builtin_amdgcn_global_load_lds(
        (const __attribute__((address_space(1))) void*)g,
        (__attribute__((address_space(3))) void*)l, 16, 0, 0);
}

// ---------- kernel 1: elementwise split of x ----------
__global__ __launch_bounds__(256) void k_split(const float* __restrict__ in,
                                               u16* __restrict__ hi,
                                               u16* __restrict__ lo, int n4) {
    int i = blockIdx.x * blockDim.x + threadIdx.x;
    if (i >= n4) return;
    const float4 v = ((const float4*)in)[i];
    float vv[4] = {v.x, v.y, v.z, v.w};
    u16 hh[4], ll[4];
#pragma unroll
    for (int j = 0; j < 4; ++j) split2(vv[j], hh[j], ll[j]);
    u16x4 hv = {hh[0], hh[1], hh[2], hh[3]};
    u16x4 lv = {ll[0], ll[1], ll[2], ll[3]};
    *(u16x4*)(hi + (size_t)i * 4) = hv;
    *(u16x4*)(lo + (size_t)i * 4) = lv;
}

// ---------- kernel 2: split + transpose a 1024x1024 weight ----------
__global__ __launch_bounds__(256) void k_splitT(const float* __restrict__ W,
                                                u16* __restrict__ hiT,
                                                u16* __restrict__ loT) {
    __shared__ float tile[32][33];
    int n0 = blockIdx.x * 32, k0 = blockIdx.y * 32;
    int tx = threadIdx.x, ty = threadIdx.y;  // (32,8)
#pragma unroll
    for (int j = 0; j < 4; ++j) {
        int r = ty + j * 8;
        tile[r][tx] = W[(size_t)(k0 + r) * ATT + n0 + tx];
    }
    __syncthreads();
#pragma unroll
    for (int j = 0; j < 4; ++j) {
        int r = ty + j * 8;              // local n
        float v = tile[tx][r];           // = W[k0+tx][n0+r]
        u16 h, l; split2(v, h, l);
        hiT[(size_t)(n0 + r) * D_MODEL + k0 + tx] = h;
        loT[(size_t)(n0 + r) * D_MODEL + k0 + tx] = l;
    }
}

// ---------- kernel 2b: u16 tiled transpose (for V^T), z selects hi/lo ----------
__global__ __launch_bounds__(256) void k_transpose(
    const u16* __restrict__ src_h, const u16* __restrict__ src_l,
    u16* __restrict__ dst_h, u16* __restrict__ dst_l, int srcld, int dstld) {
    __shared__ u16 t[64][72];
    const u16* src = blockIdx.z ? src_l : src_h;
    u16* dst = blockIdx.z ? dst_l : dst_h;
    int n0 = blockIdx.x * 64, m0 = blockIdx.y * 64;
    int tid = threadIdx.x;
    int r = tid >> 2, c16 = (tid & 3) * 16;
    *(u16x8*)&t[r][c16]     = *(const u16x8*)&src[(size_t)(m0 + r) * srcld + n0 + c16];
    *(u16x8*)&t[r][c16 + 8] = *(const u16x8*)&src[(size_t)(m0 + r) * srcld + n0 + c16 + 8];
    __syncthreads();
    u16x8 o0, o1;
#pragma unroll
    for (int j = 0; j < 8; ++j) { o0[j] = t[c16 + j][r]; o1[j] = t[c16 + 8 + j][r]; }
    *(u16x8*)&dst[(size_t)(n0 + r) * dstld + m0 + c16]     = o0;
    *(u16x8*)&dst[(size_t)(n0 + r) * dstld + m0 + c16 + 8] = o1;
}

// ---------- kernel 3: split-bf16 GEMM via global_load_lds + XOR swizzle ----------
// C[M][N] = A[M][K] * B^T[N][K] + bias.  BM = MF*32, BN = 128, BK = 32.
template <int MF, int SPLIT_OUT>
__global__ __launch_bounds__(256) void k_gemm(
    const u16* __restrict__ Ah, const u16* __restrict__ Al,
    const u16* __restrict__ Bh, const u16* __restrict__ Bl,
    const float* __restrict__ bq, const float* __restrict__ bk,
    const float* __restrict__ bv,
    float* __restrict__ Co, u16* __restrict__ Ch, u16* __restrict__ Cl,
    int M, int N, int K, int NBX) {
    constexpr int BM = MF * 32;
    constexpr int SAe = BM * 32;               // elems per A buffer
    constexpr int NCH = (2 * BM + 256) / 16;   // 1KB chunks per K-step
    constexpr int CPW = NCH / 4;
    __shared__ u16 sh[(2 * BM + 256) * 32];

    int tid = threadIdx.x;
    int wave = tid >> 6, lane = tid & 63, lg = lane >> 4, ln = lane & 15;
    int wm = wave >> 1, wn = wave & 1;

    int nb = gridDim.x;
    int bs = (blockIdx.x & 7) * (nb >> 3) + (blockIdx.x >> 3);  // XCD-chunked
    int bx = bs % NBX, by = bs / NBX;
    int m0 = by * BM, n0 = bx * 128;

    f4 acc[MF][4];
#pragma unroll
    for (int i = 0; i < MF; ++i)
#pragma unroll
        for (int j = 0; j < 4; ++j) acc[i][j] = f4{0.f, 0.f, 0.f, 0.f};

    // hoisted staging source pointers (advance by 32 elems per K-step)
    const u16* gp[CPW];
#pragma unroll
    for (int j = 0; j < CPW; ++j) {
        int c = wave * CPW + j;
        int bo = c << 10;  // byte offset into sh (wave-uniform)
        const u16* base; int local, r0;
        if (bo < BM * 64)                { base = Ah; local = bo;                 r0 = m0; }
        else if (bo < 2 * BM * 64)       { base = Al; local = bo - BM * 64;       r0 = m0; }
        else if (bo < 2 * BM * 64 + 8192){ base = Bh; local = bo - 2 * BM * 64;   r0 = n0; }
        else                             { base = Bl; local = bo - 2 * BM * 64 - 8192; r0 = n0; }
        int lo2 = local + lane * 16;
        int row = lo2 >> 6;
        int cb  = (lo2 >> 4) & 3;
        int cbs = cb ^ ((row >> 1) & 3);      // inverse-swizzled SOURCE
        gp[j] = base + (size_t)(r0 + row) * K + cbs * 8;
    }

    // hoisted fragment read offsets (loop-invariant)
    int offA[MF], offB[4];
#pragma unroll
    for (int mf = 0; mf < MF; ++mf) {
        int row = wm * (MF * 16) + mf * 16 + ln;
        offA[mf] = row * 32 + ((lg ^ ((row >> 1) & 3)) << 3);
    }
#pragma unroll
    for (int nf = 0; nf < 4; ++nf) {
        int row = wn * 64 + nf * 16 + ln;
        offB[nf] = row * 32 + ((lg ^ ((row >> 1) & 3)) << 3);
    }

    for (int kk = 0; kk < K; kk += 32) {
#pragma unroll
        for (int j = 0; j < CPW; ++j) {
            gload16(gp[j], (char*)sh + ((wave * CPW + j) << 10));
            gp[j] += 32;
        }
        __syncthreads();

        u16x8 a_h[MF], a_l[MF], b_h[4], b_l[4];
#pragma unroll
        for (int mf = 0; mf < MF; ++mf) {
            a_h[mf] = *(const u16x8*)&sh[offA[mf]];
            a_l[mf] = *(const u16x8*)&sh[SAe + offA[mf]];
        }
#pragma unroll
        for (int nf = 0; nf < 4; ++nf) {
            b_h[nf] = *(const u16x8*)&sh[2 * SAe + offB[nf]];
            b_l[nf] = *(const u16x8*)&sh[2 * SAe + 4096 + offB[nf]];
        }
#pragma unroll
        for (int mf = 0; mf < MF; ++mf)
#pragma unroll
            for (int nf = 0; nf < 4; ++nf) {
                acc[mf][nf] = mfma16(a_h[mf], b_h[nf], acc[mf][nf]);
                acc[mf][nf] = mfma16(a_h[mf], b_l[nf], acc[mf][nf]);
                acc[mf][nf] = mfma16(a_l[mf], b_h[nf], acc[mf][nf]);
            }
        __syncthreads();
    }

#pragma unroll
    for (int mf = 0; mf < MF; ++mf)
#pragma unroll
        for (int nf = 0; nf < 4; ++nf) {
            int col = n0 + wn * 64 + nf * 16 + ln;
            float bb;
            if (bk) bb = col < 1024 ? bq[col] : (col < 2048 ? bk[col - 1024] : bv[col - 2048]);
            else    bb = bq[col];
#pragma unroll
            for (int r = 0; r < 4; ++r) {
                int row = m0 + wm * (MF * 16) + mf * 16 + lg * 4 + r;
                float v = acc[mf][nf][r] + bb;
                if (SPLIT_OUT) {
                    u16 h, l; split2(v, h, l);
                    Ch[(size_t)row * N + col] = h;
                    Cl[(size_t)row * N + col] = l;
                } else {
                    Co[(size_t)row * N + col] = v;
                }
            }
        }
}

// ---------- kernel 4: flash attention, QBLK=128, double-buffered K/V ----------
// LDS (u16): buf0 [0,16384): Kh,Kl,Vh,Vl (4096 each); buf1 [16384,32768);
// P [32768,40960) = 80KB total. 128B rows, swizzle kb' = kb ^ (row&7).
#define ATTN_SCALE 0.18033688f  /* 0.125 * log2(e) */

__global__ __launch_bounds__(256, 2) void k_attn(
    const u16* __restrict__ qkv_h, const u16* __restrict__ qkv_l,
    const u16* __restrict__ vt_h, const u16* __restrict__ vt_l,
    u16* __restrict__ Oh, u16* __restrict__ Ol) {
    __shared__ u16 sh[40960];
    int tid = threadIdx.x;
    int w = tid >> 6, lane = tid & 63, lg = lane >> 4, ln = lane & 15;

    int bs = (blockIdx.x & 7) * 64 + (blockIdx.x >> 3);  // XCD-chunked, 512 blocks
    int qt = bs & 15, h = (bs >> 4) & 15, b = bs >> 8;
    int q0 = qt * 128;

    // Q fragments in registers (wave owns 32 q-rows)
    u16x8 qh[2][2], ql[2][2];
#pragma unroll
    for (int mf = 0; mf < 2; ++mf) {
        int row = q0 + w * 32 + mf * 16 + ln;
        const u16* ph_ = qkv_h + (size_t)(b * SEQ + row) * 3072 + h * HDIM;
        const u16* pl_ = qkv_l + (size_t)(b * SEQ + row) * 3072 + h * HDIM;
#pragma unroll
        for (int ks = 0; ks < 2; ++ks) {
            qh[mf][ks] = *(const u16x8*)(ph_ + ks * 32 + lg * 8);
            ql[mf][ks] = *(const u16x8*)(pl_ + ks * 32 + lg * 8);
        }
    }

    f4 acco[2][4], accl[2];
#pragma unroll
    for (int i = 0; i < 2; ++i) {
#pragma unroll
        for (int j = 0; j < 4; ++j) acco[i][j] = f4{0.f, 0.f, 0.f, 0.f};
        accl[i] = f4{0.f, 0.f, 0.f, 0.f};
    }
    float run_m[2][4];
#pragma unroll
    for (int i = 0; i < 2; ++i)
#pragma unroll
        for (int r = 0; r < 4; ++r) run_m[i][r] = -INFINITY;

    u16x8 ones;
#pragma unroll
    for (int j = 0; j < 8; ++j) ones[j] = 0x3F80;  // bf16 1.0

    // staging geometry: wave w loads buffer-type w (0:Kh 1:Kl 2:Vh 3:Vl)
    // per j: row = j*8 + (lane>>3), kbs = (lane&7)^(lane>>3)
    const u16* gp[8];
    {
        int row = (lane >> 3), kbs = (lane & 7) ^ (lane >> 3);
        const u16* base;
        if (w == 0)      base = qkv_h + (size_t)(b * SEQ) * 3072 + 1024 + h * HDIM;
        else if (w == 1) base = qkv_l + (size_t)(b * SEQ) * 3072 + 1024 + h * HDIM;
        else if (w == 2) base = vt_h + (size_t)(h * HDIM) * M_ROWS + b * SEQ;
        else             base = vt_l + (size_t)(h * HDIM) * M_ROWS + b * SEQ;
        size_t rs = (w < 2) ? 3072 : M_ROWS;
#pragma unroll
        for (int j = 0; j < 8; ++j)
            gp[j] = base + (size_t)(j * 8 + row) * rs + kbs * 8;
    }
    const int gstride = (w < 2) ? 64 * 3072 : 64;
    const int sbase = w << 13;  // byte base of this wave's chunks within a buffer

#define STAGE(BSEL) do { _Pragma("unroll") \
    for (int j_ = 0; j_ < 8; ++j_) \
        gload16(gp[j_], (char*)sh + sbase + (j_ << 10) + (BSEL) * 32768); \
} while (0)
#define ADV() do { _Pragma("unroll") for (int j_ = 0; j_ < 8; ++j_) gp[j_] += gstride; } while (0)
#define WAITB(N) do { asm volatile("s_waitcnt vmcnt(" #N ")" ::: "memory"); \
    __builtin_amdgcn_s_barrier(); } while (0)
#define BAR() __builtin_amdgcn_s_barrier()

    // hoisted ds_read offsets (u16 indices, relative to buffer base)
    int offQK[4][2], offV[4][2], offPr[2][2];
#pragma unroll
    for (int nf = 0; nf < 4; ++nf) {
        int krow = nf * 16 + ln;
#pragma unroll
        for (int ks = 0; ks < 2; ++ks) {
            offQK[nf][ks] = krow * 64 + (((4 * ks + lg) ^ (krow & 7)) << 3);
            offV[nf][ks]  = offQK[nf][ks];  // same geometry for V rows
        }
    }
#pragma unroll
    for (int mf = 0; mf < 2; ++mf) {
        int prow = w * 32 + mf * 16 + ln;
#pragma unroll
        for (int ks = 0; ks < 2; ++ks)
            offPr[mf][ks] = 32768 + prow * 64 + (((4 * ks + lg) ^ (prow & 7)) << 3);
    }

#define COMPUTE(BASE) do { \
    f4 s[2][4]; \
    _Pragma("unroll") for (int i = 0; i < 2; ++i) \
    _Pragma("unroll") for (int j = 0; j < 4; ++j) s[i][j] = f4{0.f, 0.f, 0.f, 0.f}; \
    _Pragma("unroll") for (int nf = 0; nf < 4; ++nf) { \
        _Pragma("unroll") for (int ks = 0; ks < 2; ++ks) { \
            u16x8 bh = *(const u16x8*)&sh[(BASE) + offQK[nf][ks]]; \
            u16x8 bl = *(const u16x8*)&sh[(BASE) + 4096 + offQK[nf][ks]]; \
            _Pragma("unroll") for (int mf = 0; mf < 2; ++mf) { \
                s[mf][nf] = mfma16(qh[mf][ks], bh, s[mf][nf]); \
                s[mf][nf] = mfma16(qh[mf][ks], bl, s[mf][nf]); \
                s[mf][nf] = mfma16(ql[mf][ks], bh, s[mf][nf]); \
            } \
        } \
    } \
    _Pragma("unroll") for (int mf = 0; mf < 2; ++mf) { \
        _Pragma("unroll") for (int r = 0; r < 4; ++r) { \
            float mx = fmaxf(fmaxf(s[mf][0][r], s[mf][1][r]), \
                             fmaxf(s[mf][2][r], s[mf][3][r])); \
            _Pragma("unroll") for (int d = 1; d < 16; d <<= 1) \
                mx = fmaxf(mx, __shfl_xor(mx, d)); \
            float mx2 = mx * ATTN_SCALE; \
            bool need = mx2 > run_m[mf][r] + 11.0f; \
            float nm = need ? mx2 : run_m[mf][r]; \
            int qrow = w * 32 + mf * 16 + lg * 4 + r; \
            int swz = qrow & 7; \
            int pbase = 32768 + qrow * 64 + (ln & 7); \
            _Pragma("unroll") for (int nf = 0; nf < 4; ++nf) { \
                float p = __builtin_amdgcn_exp2f(s[mf][nf][r] * ATTN_SCALE - nm); \
                sh[pbase + (((nf * 2 + (ln >> 3)) ^ swz) << 3)] = f32_to_bf16(p); \
            } \
            if (__any((int)need)) { \
                float corr = __builtin_amdgcn_exp2f(run_m[mf][r] - nm); \
                _Pragma("unroll") for (int nf = 0; nf < 4; ++nf) acco[mf][nf][r] *= corr; \
                accl[mf][r] *= corr; \
                run_m[mf][r] = nm; \
            } \
        } \
    } \
    /* P wave-private: no barrier */ \
    _Pragma("unroll") for (int ks = 0; ks < 2; ++ks) { \
        u16x8 pa[2]; \
        _Pragma("unroll") for (int mf = 0; mf < 2; ++mf) \
            pa[mf] = *(const u16x8*)&sh[offPr[mf][ks]]; \
        _Pragma("unroll") for (int nf = 0; nf < 4; ++nf) { \
            u16x8 vh = *(const u16x8*)&sh[(BASE) + 8192 + offV[nf][ks]]; \
            u16x8 vl = *(const u16x8*)&sh[(BASE) + 12288 + offV[nf][ks]]; \
            _Pragma("unroll") for (int mf = 0; mf < 2; ++mf) { \
                acco[mf][nf] = mfma16(pa[mf], vh, acco[mf][nf]); \
                acco[mf][nf] = mfma16(pa[mf], vl, acco[mf][nf]); \
            } \
        } \
        accl[0] = mfma16(pa[0], ones, accl[0]); \
        accl[1] = mfma16(pa[1], ones, accl[1]); \
    } \
} while (0)

    // ---- pipelined K/V loop: 32 tiles, 2 buffers ----
    STAGE(0); ADV();
    for (int t = 0; t < 30; t += 2) {
        STAGE(1); ADV();
        WAITB(8);
        COMPUTE(0);
        BAR();
        STAGE(0); ADV();
        WAITB(8);
        COMPUTE(16384);
        BAR();
    }
    STAGE(1);
    WAITB(8);
    COMPUTE(0);
    BAR();
    WAITB(0);
    COMPUTE(16384);

    // ---- epilogue: O /= l, split-write ----
#pragma unroll
    for (int mf = 0; mf < 2; ++mf)
#pragma unroll
        for (int nf = 0; nf < 4; ++nf) {
            int col = h * HDIM + nf * 16 + ln;
#pragma unroll
            for (int r = 0; r < 4; ++r) {
                int row = q0 + w * 32 + mf * 16 + lg * 4 + r;
                float v = acco[mf][nf][r] / accl[mf][r];
                u16 hh, ll; split2(v, hh, ll);
                Oh[(size_t)(b * SEQ + row) * ATT + col] = hh;
                Ol[(size_t)(b * SEQ + row) * ATT + col] = ll;
            }
        }
#undef STAGE
#undef ADV
#undef WAITB
#undef BAR
#undef COMPUTE
}

// ---------- launcher ----------
extern "C" void kernel_launch(void* const* d_in, const int* in_sizes, int n_in,
                              void* d_out, int out_size, void* d_ws, size_t ws_size,
                              hipStream_t stream) {
    const float* x  = (const float*)d_in[0];
    const float* Wq = (const float*)d_in[1];
    const float* bq = (const float*)d_in[2];
    const float* Wk = (const float*)d_in[3];
    const float* bk = (const float*)d_in[4];
    const float* Wv = (const float*)d_in[5];
    const float* bv = (const float*)d_in[6];
    const float* Wo = (const float*)d_in[7];
    const float* bo = (const float*)d_in[8];
    float* out = (float*)d_out;

    const size_t MK = (size_t)M_ROWS * ATT;   // 4M elems
    const size_t WE = (size_t)D_MODEL * ATT;  // 1M elems
    const size_t M3 = (size_t)M_ROWS * 3072;  // fused qkv elems

    char* p = (char*)d_ws;
    auto alloc = [&](size_t bytes) -> u16* {
        u16* r = (u16*)p;
        p += (bytes + 255) & ~(size_t)255;
        return r;
    };
    u16* x_hi  = alloc(MK * 2); u16* x_lo  = alloc(MK * 2);
    u16* wT_h  = alloc(3 * WE * 2); u16* wT_l  = alloc(3 * WE * 2);  // [Wq;Wk;Wv]^T stacked
    u16* woT_h = alloc(WE * 2); u16* woT_l = alloc(WE * 2);
    u16* qkv_h = alloc(M3 * 2); u16* qkv_l = alloc(M3 * 2);          // [M][3072]
    u16* vt_h  = alloc(MK * 2); u16* vt_l  = alloc(MK * 2);          // V^T [1024][4096]
    u16* at_h = x_hi; u16* at_l = x_lo;  // attention out reuses x buffers

    k_split<<<dim3((unsigned)(MK / 4 / 256)), 256, 0, stream>>>(x, x_hi, x_lo, (int)(MK / 4));

    dim3 bt(32, 8), gt(32, 32);
    k_splitT<<<gt, bt, 0, stream>>>(Wq, wT_h, wT_l);
    k_splitT<<<gt, bt, 0, stream>>>(Wk, wT_h + WE, wT_l + WE);
    k_splitT<<<gt, bt, 0, stream>>>(Wv, wT_h + 2 * WE, wT_l + 2 * WE);
    k_splitT<<<gt, bt, 0, stream>>>(Wo, woT_h, woT_l);

    // fused QKV: [4096 x 3072] = x[4096x1024] @ [Wq|Wk|Wv], 768 blocks (3/CU)
    k_gemm<4, 1><<<768, 256, 0, stream>>>(x_hi, x_lo, wT_h, wT_l, bq, bk, bv,
                                          nullptr, qkv_h, qkv_l, M_ROWS, 3072, 1024, 24);

    // V^T: qkv cols [2048,3072) -> vt [1024][4096]
    k_transpose<<<dim3(16, 64, 2), 256, 0, stream>>>(qkv_h + 2048, qkv_l + 2048,
                                                     vt_h, vt_l, 3072, M_ROWS);

    // attention: 512 blocks (2/CU), QBLK=128, double-buffered K/V
    k_attn<<<512, 256, 0, stream>>>(qkv_h, qkv_l, vt_h, vt_l, at_h, at_l);

    // Wo: BM=64 -> 512 blocks (2/CU)
    k_gemm<2, 0><<<512, 256, 0, stream>>>(at_h, at_l, woT_h, woT_l, bo, nullptr, nullptr,
                                          out, nullptr, nullptr, M_ROWS, 1024, 1024, 8);
}

// Round 5
// 330.991 us; speedup vs baseline: 1.2986x; 1.1198x over previous
//
#include <hip/hip_runtime.h>
#include <hip/hip_bf16.h>
#include <math.h>

#define D_MODEL 1024
#define ATT 1024
#define NHEAD 16
#define HDIM 64
#define BATCH 2
#define SEQ 2048
#define M_ROWS (BATCH * SEQ) /* 4096 */

typedef unsigned short u16;
typedef unsigned int u32;
typedef __bf16 bf16x8 __attribute__((ext_vector_type(8)));
typedef float f4 __attribute__((ext_vector_type(4)));
typedef u16 u16x8 __attribute__((ext_vector_type(8)));
typedef u16 u16x4 __attribute__((ext_vector_type(4)));

static_assert(sizeof(u16x8) == 16, "u16x8 must be 16B");

// ---------- bf16 split helpers ----------
__device__ __forceinline__ u16 f32_to_bf16(float f) {
    union { float f; unsigned u; } c; c.f = f;
    unsigned u = c.u;
    return (u16)((u + 0x7FFFu + ((u >> 16) & 1u)) >> 16);  // RNE
}
__device__ __forceinline__ float bf16_to_f32(u16 h) {
    union { unsigned u; float f; } c; c.u = ((unsigned)h) << 16;
    return c.f;
}
__device__ __forceinline__ void split2(float f, u16& hi, u16& lo) {
    hi = f32_to_bf16(f);
    lo = f32_to_bf16(f - bf16_to_f32(hi));
}

__device__ __forceinline__ f4 mfma16(u16x8 a, u16x8 b, f4 c) {
    union U { u16x8 u; bf16x8 b; };
    U ua, ub; ua.u = a; ub.u = b;
    return __builtin_amdgcn_mfma_f32_16x16x32_bf16(ua.b, ub.b, c, 0, 0, 0);
}

// async global->LDS, 16B per lane, dest = uniform base + lane*16
__device__ __forceinline__ void gload16(const void* g, void* l) {
    __builtin_amdgcn_global_load_lds(
        (const __attribute__((address_space(1))) void*)g,
        (__attribute__((address_space(3))) void*)l, 16, 0, 0);
}

template <int N>
__device__ __forceinline__ void waitcnt_vm() {
    if constexpr (N == 0)      asm volatile("s_waitcnt vmcnt(0)" ::: "memory");
    else if constexpr (N == 4) asm volatile("s_waitcnt vmcnt(4)" ::: "memory");
    else if constexpr (N == 6) asm volatile("s_waitcnt vmcnt(6)" ::: "memory");
    else if constexpr (N == 8) asm volatile("s_waitcnt vmcnt(8)" ::: "memory");
}
#define BARRIER() __builtin_amdgcn_s_barrier()

// ---------- kernel 1: elementwise split of x ----------
__global__ __launch_bounds__(256) void k_split(const float* __restrict__ in,
                                               u16* __restrict__ hi,
                                               u16* __restrict__ lo, int n4) {
    int i = blockIdx.x * blockDim.x + threadIdx.x;
    if (i >= n4) return;
    const float4 v = ((const float4*)in)[i];
    float vv[4] = {v.x, v.y, v.z, v.w};
    u16 hh[4], ll[4];
#pragma unroll
    for (int j = 0; j < 4; ++j) split2(vv[j], hh[j], ll[j]);
    u16x4 hv = {hh[0], hh[1], hh[2], hh[3]};
    u16x4 lv = {ll[0], ll[1], ll[2], ll[3]};
    *(u16x4*)(hi + (size_t)i * 4) = hv;
    *(u16x4*)(lo + (size_t)i * 4) = lv;
}

// ---------- kernel 2: split + transpose a 1024x1024 weight ----------
__global__ __launch_bounds__(256) void k_splitT(const float* __restrict__ W,
                                                u16* __restrict__ hiT,
                                                u16* __restrict__ loT) {
    __shared__ float tile[32][33];
    int n0 = blockIdx.x * 32, k0 = blockIdx.y * 32;
    int tx = threadIdx.x, ty = threadIdx.y;  // (32,8)
#pragma unroll
    for (int j = 0; j < 4; ++j) {
        int r = ty + j * 8;
        tile[r][tx] = W[(size_t)(k0 + r) * ATT + n0 + tx];
    }
    __syncthreads();
#pragma unroll
    for (int j = 0; j < 4; ++j) {
        int r = ty + j * 8;              // local n
        float v = tile[tx][r];           // = W[k0+tx][n0+r]
        u16 h, l; split2(v, h, l);
        hiT[(size_t)(n0 + r) * D_MODEL + k0 + tx] = h;
        loT[(size_t)(n0 + r) * D_MODEL + k0 + tx] = l;
    }
}

// ---------- kernel 2b: u16 tiled transpose (for V^T), z selects hi/lo ----------
__global__ __launch_bounds__(256) void k_transpose(
    const u16* __restrict__ src_h, const u16* __restrict__ src_l,
    u16* __restrict__ dst_h, u16* __restrict__ dst_l, int srcld, int dstld) {
    __shared__ u16 t[64][72];
    const u16* src = blockIdx.z ? src_l : src_h;
    u16* dst = blockIdx.z ? dst_l : dst_h;
    int n0 = blockIdx.x * 64, m0 = blockIdx.y * 64;
    int tid = threadIdx.x;
    int r = tid >> 2, c16 = (tid & 3) * 16;
    *(u16x8*)&t[r][c16]     = *(const u16x8*)&src[(size_t)(m0 + r) * srcld + n0 + c16];
    *(u16x8*)&t[r][c16 + 8] = *(const u16x8*)&src[(size_t)(m0 + r) * srcld + n0 + c16 + 8];
    __syncthreads();
    u16x8 o0, o1;
#pragma unroll
    for (int j = 0; j < 8; ++j) { o0[j] = t[c16 + j][r]; o1[j] = t[c16 + 8 + j][r]; }
    *(u16x8*)&dst[(size_t)(n0 + r) * dstld + m0 + c16]     = o0;
    *(u16x8*)&dst[(size_t)(n0 + r) * dstld + m0 + c16 + 8] = o1;
}

// ---------- kernel 3: split-bf16 GEMM, double-buffered LDS + counted vmcnt ----------
// C[M][N] = A[M][K] * B^T[N][K] + bias.  BM = MF*32, BN = 128, BK = 32.
// Per-buffer LDS layout (bytes): Ah[0,BM*64) Al[..) Bh[..+8192) Bl[..+8192)
// swizzle: 16B block cb' = cb ^ ((row>>1)&3) (pre-swizzled source + swizzled read).
template <int MF, int SPLIT_OUT>
__global__ __launch_bounds__(256) void k_gemm(
    const u16* __restrict__ Ah, const u16* __restrict__ Al,
    const u16* __restrict__ Bh, const u16* __restrict__ Bl,
    const float* __restrict__ bq, const float* __restrict__ bk,
    const float* __restrict__ bv,
    float* __restrict__ Co, u16* __restrict__ Ch, u16* __restrict__ Cl,
    int M, int N, int K, int NBX) {
    constexpr int BM = MF * 32;
    constexpr int SAe = BM * 32;               // u16 elems per A buffer
    constexpr int NCH = (2 * BM + 256) / 16;   // 1KB chunks per K-step
    constexpr int CPW = NCH / 4;               // chunks per wave (8 or 6)
    constexpr int BUFE = (2 * BM + 256) * 32;  // u16 elems per K-step buffer
    __shared__ u16 sh[2 * BUFE];

    int tid = threadIdx.x;
    int wave = tid >> 6, lane = tid & 63, lg = lane >> 4, ln = lane & 15;
    int wm = wave >> 1, wn = wave & 1;

    int nb = gridDim.x;
    int bs = (blockIdx.x & 7) * (nb >> 3) + (blockIdx.x >> 3);  // XCD-chunked
    int bx = bs % NBX, by = bs / NBX;
    int m0 = by * BM, n0 = bx * 128;

    f4 acc[MF][4];
#pragma unroll
    for (int i = 0; i < MF; ++i)
#pragma unroll
        for (int j = 0; j < 4; ++j) acc[i][j] = f4{0.f, 0.f, 0.f, 0.f};

    // hoisted staging source pointers (advance by 32 elems per K-step)
    const u16* gp[CPW];
#pragma unroll
    for (int j = 0; j < CPW; ++j) {
        int c = wave * CPW + j;
        int bo = c << 10;  // byte offset within a K-step buffer (wave-uniform)
        const u16* base; int local, r0;
        if (bo < BM * 64)                { base = Ah; local = bo;                 r0 = m0; }
        else if (bo < 2 * BM * 64)       { base = Al; local = bo - BM * 64;       r0 = m0; }
        else if (bo < 2 * BM * 64 + 8192){ base = Bh; local = bo - 2 * BM * 64;   r0 = n0; }
        else                             { base = Bl; local = bo - 2 * BM * 64 - 8192; r0 = n0; }
        int lo2 = local + lane * 16;
        int row = lo2 >> 6;
        int cb  = (lo2 >> 4) & 3;
        int cbs = cb ^ ((row >> 1) & 3);      // inverse-swizzled SOURCE
        gp[j] = base + (size_t)(r0 + row) * K + cbs * 8;
    }

    // hoisted fragment read offsets (loop-invariant)
    int offA[MF], offB[4];
#pragma unroll
    for (int mf = 0; mf < MF; ++mf) {
        int row = wm * (MF * 16) + mf * 16 + ln;
        offA[mf] = row * 32 + ((lg ^ ((row >> 1) & 3)) << 3);
    }
#pragma unroll
    for (int nf = 0; nf < 4; ++nf) {
        int row = wn * 64 + nf * 16 + ln;
        offB[nf] = row * 32 + ((lg ^ ((row >> 1) & 3)) << 3);
    }

    auto stage = [&](int bsel) {
#pragma unroll
        for (int j = 0; j < CPW; ++j)
            gload16(gp[j], (char*)sh + bsel * (BUFE * 2) + ((wave * CPW + j) << 10));
    };
    auto adv = [&]() {
#pragma unroll
        for (int j = 0; j < CPW; ++j) gp[j] += 32;
    };
    auto compute = [&](int sb) {  // sb = u16 index base of buffer
        u16x8 a_h[MF], a_l[MF], b_h[4], b_l[4];
#pragma unroll
        for (int mf = 0; mf < MF; ++mf) {
            a_h[mf] = *(const u16x8*)&sh[sb + offA[mf]];
            a_l[mf] = *(const u16x8*)&sh[sb + SAe + offA[mf]];
        }
#pragma unroll
        for (int nf = 0; nf < 4; ++nf) {
            b_h[nf] = *(const u16x8*)&sh[sb + 2 * SAe + offB[nf]];
            b_l[nf] = *(const u16x8*)&sh[sb + 2 * SAe + 4096 + offB[nf]];
        }
#pragma unroll
        for (int mf = 0; mf < MF; ++mf)
#pragma unroll
            for (int nf = 0; nf < 4; ++nf) {
                acc[mf][nf] = mfma16(a_h[mf], b_h[nf], acc[mf][nf]);
                acc[mf][nf] = mfma16(a_h[mf], b_l[nf], acc[mf][nf]);
                acc[mf][nf] = mfma16(a_l[mf], b_h[nf], acc[mf][nf]);
            }
    };

    // ---- pipelined K loop: K/32 steps (must be even), 2 buffers ----
    const int NS = K / 32;
    stage(0); adv();
    for (int t = 0; t < NS - 2; t += 2) {
        stage(1); adv();
        waitcnt_vm<CPW>(); BARRIER();
        compute(0);
        BARRIER();
        stage(0); adv();
        waitcnt_vm<CPW>(); BARRIER();
        compute(BUFE);
        BARRIER();
    }
    stage(1);
    waitcnt_vm<CPW>(); BARRIER();
    compute(0);
    BARRIER();
    waitcnt_vm<0>(); BARRIER();
    compute(BUFE);

#pragma unroll
    for (int mf = 0; mf < MF; ++mf)
#pragma unroll
        for (int nf = 0; nf < 4; ++nf) {
            int col = n0 + wn * 64 + nf * 16 + ln;
            float bb;
            if (bk) bb = col < 1024 ? bq[col] : (col < 2048 ? bk[col - 1024] : bv[col - 2048]);
            else    bb = bq[col];
#pragma unroll
            for (int r = 0; r < 4; ++r) {
                int row = m0 + wm * (MF * 16) + mf * 16 + lg * 4 + r;
                float v = acc[mf][nf][r] + bb;
                if (SPLIT_OUT) {
                    u16 h, l; split2(v, h, l);
                    Ch[(size_t)row * N + col] = h;
                    Cl[(size_t)row * N + col] = l;
                } else {
                    Co[(size_t)row * N + col] = v;
                }
            }
        }
}

// ---------- kernel 4: flash attention, QBLK=256, 8 waves, double-buffered K/V ----
// LDS (u16): buf0 [0,16384): Kh,Kl,Vh,Vl (4096 each); buf1 [16384,32768);
// P [32768,49152) = 96KB total. 128B rows, swizzle kb' = kb ^ (row&7).
#define ATTN_SCALE 0.18033688f  /* 0.125 * log2(e) */

__global__ __launch_bounds__(512, 1) void k_attn(
    const u16* __restrict__ qkv_h, const u16* __restrict__ qkv_l,
    const u16* __restrict__ vt_h, const u16* __restrict__ vt_l,
    u16* __restrict__ Oh, u16* __restrict__ Ol) {
    __shared__ u16 sh[49152];
    int tid = threadIdx.x;
    int w = tid >> 6, lane = tid & 63, lg = lane >> 4, ln = lane & 15;

    int bs = (blockIdx.x & 7) * 32 + (blockIdx.x >> 3);  // XCD-chunked, 256 blocks
    int qt = bs & 7, h = (bs >> 3) & 15, b = bs >> 7;
    int q0 = qt * 256;

    // Q fragments in registers (wave owns 32 q-rows)
    u16x8 qh[2][2], ql[2][2];
#pragma unroll
    for (int mf = 0; mf < 2; ++mf) {
        int row = q0 + w * 32 + mf * 16 + ln;
        const u16* ph_ = qkv_h + (size_t)(b * SEQ + row) * 3072 + h * HDIM;
        const u16* pl_ = qkv_l + (size_t)(b * SEQ + row) * 3072 + h * HDIM;
#pragma unroll
        for (int ks = 0; ks < 2; ++ks) {
            qh[mf][ks] = *(const u16x8*)(ph_ + ks * 32 + lg * 8);
            ql[mf][ks] = *(const u16x8*)(pl_ + ks * 32 + lg * 8);
        }
    }

    f4 acco[2][4], accl[2];
#pragma unroll
    for (int i = 0; i < 2; ++i) {
#pragma unroll
        for (int j = 0; j < 4; ++j) acco[i][j] = f4{0.f, 0.f, 0.f, 0.f};
        accl[i] = f4{0.f, 0.f, 0.f, 0.f};
    }
    float run_m[2][4];
#pragma unroll
    for (int i = 0; i < 2; ++i)
#pragma unroll
        for (int r = 0; r < 4; ++r) run_m[i][r] = -INFINITY;

    u16x8 ones;
#pragma unroll
    for (int j = 0; j < 8; ++j) ones[j] = 0x3F80;  // bf16 1.0

    // staging: wave w stages buffer-type (w>>1) half (w&1): 4 chunks of 1KB
    int bt = w >> 1, hf = w & 1;
    const u16* gp[4];
    {
        int row0 = hf * 32 + (lane >> 3);
        int kbs = (lane & 7) ^ (lane >> 3);
        const u16* base;
        if (bt == 0)      base = qkv_h + (size_t)(b * SEQ) * 3072 + 1024 + h * HDIM;
        else if (bt == 1) base = qkv_l + (size_t)(b * SEQ) * 3072 + 1024 + h * HDIM;
        else if (bt == 2) base = vt_h + (size_t)(h * HDIM) * M_ROWS + b * SEQ;
        else              base = vt_l + (size_t)(h * HDIM) * M_ROWS + b * SEQ;
        size_t rs = (bt < 2) ? 3072 : M_ROWS;
#pragma unroll
        for (int j = 0; j < 4; ++j)
            gp[j] = base + (size_t)(row0 + j * 8) * rs + kbs * 8;
    }
    const int gstride = (bt < 2) ? 64 * 3072 : 64;
    const int sbase = bt * 8192 + hf * 4096;  // byte base within a KV buffer

    auto stage = [&](int bsel) {
#pragma unroll
        for (int j = 0; j < 4; ++j)
            gload16(gp[j], (char*)sh + sbase + (j << 10) + bsel * 32768);
    };
    auto adv = [&]() {
#pragma unroll
        for (int j = 0; j < 4; ++j) gp[j] += gstride;
    };

    // hoisted ds_read offsets (u16 indices, relative to buffer base)
    int offQK[4][2], offPr[2][2];
#pragma unroll
    for (int nf = 0; nf < 4; ++nf) {
        int krow = nf * 16 + ln;
#pragma unroll
        for (int ks = 0; ks < 2; ++ks)
            offQK[nf][ks] = krow * 64 + (((4 * ks + lg) ^ (krow & 7)) << 3);
    }
#pragma unroll
    for (int mf = 0; mf < 2; ++mf) {
        int prow = w * 32 + mf * 16 + ln;
#pragma unroll
        for (int ks = 0; ks < 2; ++ks)
            offPr[mf][ks] = 32768 + prow * 64 + (((4 * ks + lg) ^ (prow & 7)) << 3);
    }

    auto compute = [&](int base) {  // base = u16 index of KV buffer
        f4 s[2][4];
#pragma unroll
        for (int i = 0; i < 2; ++i)
#pragma unroll
            for (int j = 0; j < 4; ++j) s[i][j] = f4{0.f, 0.f, 0.f, 0.f};
#pragma unroll
        for (int nf = 0; nf < 4; ++nf) {
#pragma unroll
            for (int ks = 0; ks < 2; ++ks) {
                u16x8 bh = *(const u16x8*)&sh[base + offQK[nf][ks]];
                u16x8 bl = *(const u16x8*)&sh[base + 4096 + offQK[nf][ks]];
#pragma unroll
                for (int mf = 0; mf < 2; ++mf) {
                    s[mf][nf] = mfma16(qh[mf][ks], bh, s[mf][nf]);
                    s[mf][nf] = mfma16(qh[mf][ks], bl, s[mf][nf]);
                    s[mf][nf] = mfma16(ql[mf][ks], bh, s[mf][nf]);
                }
            }
        }
#pragma unroll
        for (int mf = 0; mf < 2; ++mf) {
#pragma unroll
            for (int r = 0; r < 4; ++r) {
                float mx = fmaxf(fmaxf(s[mf][0][r], s[mf][1][r]),
                                 fmaxf(s[mf][2][r], s[mf][3][r]));
#pragma unroll
                for (int d = 1; d < 16; d <<= 1) mx = fmaxf(mx, __shfl_xor(mx, d));
                float mx2 = mx * ATTN_SCALE;
                bool need = mx2 > run_m[mf][r] + 11.0f;
                float nm = need ? mx2 : run_m[mf][r];
                int qrow = w * 32 + mf * 16 + lg * 4 + r;
                int swz = qrow & 7;
                int pbase = 32768 + qrow * 64 + (ln & 7);
#pragma unroll
                for (int nf = 0; nf < 4; ++nf) {
                    float p = __builtin_amdgcn_exp2f(s[mf][nf][r] * ATTN_SCALE - nm);
                    sh[pbase + (((nf * 2 + (ln >> 3)) ^ swz) << 3)] = f32_to_bf16(p);
                }
                if (__any((int)need)) {
                    float corr = __builtin_amdgcn_exp2f(run_m[mf][r] - nm);
#pragma unroll
                    for (int nf = 0; nf < 4; ++nf) acco[mf][nf][r] *= corr;
                    accl[mf][r] *= corr;
                    run_m[mf][r] = nm;
                }
            }
        }
        // P wave-private: no barrier
#pragma unroll
        for (int ks = 0; ks < 2; ++ks) {
            u16x8 pa[2];
#pragma unroll
            for (int mf = 0; mf < 2; ++mf)
                pa[mf] = *(const u16x8*)&sh[offPr[mf][ks]];
#pragma unroll
            for (int nf = 0; nf < 4; ++nf) {
                u16x8 vh = *(const u16x8*)&sh[base + 8192 + offQK[nf][ks]];
                u16x8 vl = *(const u16x8*)&sh[base + 12288 + offQK[nf][ks]];
#pragma unroll
                for (int mf = 0; mf < 2; ++mf) {
                    acco[mf][nf] = mfma16(pa[mf], vh, acco[mf][nf]);
                    acco[mf][nf] = mfma16(pa[mf], vl, acco[mf][nf]);
                }
            }
            accl[0] = mfma16(pa[0], ones, accl[0]);
            accl[1] = mfma16(pa[1], ones, accl[1]);
        }
    };

    // ---- pipelined K/V loop: 32 tiles, 2 buffers ----
    stage(0); adv();
    for (int t = 0; t < 30; t += 2) {
        stage(1); adv();
        waitcnt_vm<4>(); BARRIER();
        compute(0);
        BARRIER();
        stage(0); adv();
        waitcnt_vm<4>(); BARRIER();
        compute(16384);
        BARRIER();
    }
    stage(1);
    waitcnt_vm<4>(); BARRIER();
    compute(0);
    BARRIER();
    waitcnt_vm<0>(); BARRIER();
    compute(16384);

    // ---- epilogue: O /= l, split-write ----
#pragma unroll
    for (int mf = 0; mf < 2; ++mf)
#pragma unroll
        for (int nf = 0; nf < 4; ++nf) {
            int col = h * HDIM + nf * 16 + ln;
#pragma unroll
            for (int r = 0; r < 4; ++r) {
                int row = q0 + w * 32 + mf * 16 + lg * 4 + r;
                float v = acco[mf][nf][r] / accl[mf][r];
                u16 hh, ll; split2(v, hh, ll);
                Oh[(size_t)(b * SEQ + row) * ATT + col] = hh;
                Ol[(size_t)(b * SEQ + row) * ATT + col] = ll;
            }
        }
}

// ---------- launcher ----------
extern "C" void kernel_launch(void* const* d_in, const int* in_sizes, int n_in,
                              void* d_out, int out_size, void* d_ws, size_t ws_size,
                              hipStream_t stream) {
    const float* x  = (const float*)d_in[0];
    const float* Wq = (const float*)d_in[1];
    const float* bq = (const float*)d_in[2];
    const float* Wk = (const float*)d_in[3];
    const float* bk = (const float*)d_in[4];
    const float* Wv = (const float*)d_in[5];
    const float* bv = (const float*)d_in[6];
    const float* Wo = (const float*)d_in[7];
    const float* bo = (const float*)d_in[8];
    float* out = (float*)d_out;

    const size_t MK = (size_t)M_ROWS * ATT;   // 4M elems
    const size_t WE = (size_t)D_MODEL * ATT;  // 1M elems
    const size_t M3 = (size_t)M_ROWS * 3072;  // fused qkv elems

    char* p = (char*)d_ws;
    auto alloc = [&](size_t bytes) -> u16* {
        u16* r = (u16*)p;
        p += (bytes + 255) & ~(size_t)255;
        return r;
    };
    u16* x_hi  = alloc(MK * 2); u16* x_lo  = alloc(MK * 2);
    u16* wT_h  = alloc(3 * WE * 2); u16* wT_l  = alloc(3 * WE * 2);  // [Wq;Wk;Wv]^T stacked
    u16* woT_h = alloc(WE * 2); u16* woT_l = alloc(WE * 2);
    u16* qkv_h = alloc(M3 * 2); u16* qkv_l = alloc(M3 * 2);          // [M][3072]
    u16* vt_h  = alloc(MK * 2); u16* vt_l  = alloc(MK * 2);          // V^T [1024][4096]
    u16* at_h = x_hi; u16* at_l = x_lo;  // attention out reuses x buffers

    k_split<<<dim3((unsigned)(MK / 4 / 256)), 256, 0, stream>>>(x, x_hi, x_lo, (int)(MK / 4));

    dim3 bt(32, 8), gt(32, 32);
    k_splitT<<<gt, bt, 0, stream>>>(Wq, wT_h, wT_l);
    k_splitT<<<gt, bt, 0, stream>>>(Wk, wT_h + WE, wT_l + WE);
    k_splitT<<<gt, bt, 0, stream>>>(Wv, wT_h + 2 * WE, wT_l + 2 * WE);
    k_splitT<<<gt, bt, 0, stream>>>(Wo, woT_h, woT_l);

    // fused QKV: [4096 x 3072] = x[4096x1024] @ [Wq|Wk|Wv], 768 blocks
    k_gemm<4, 1><<<768, 256, 0, stream>>>(x_hi, x_lo, wT_h, wT_l, bq, bk, bv,
                                          nullptr, qkv_h, qkv_l, M_ROWS, 3072, 1024, 24);

    // V^T: qkv cols [2048,3072) -> vt [1024][4096]
    k_transpose<<<dim3(16, 64, 2), 256, 0, stream>>>(qkv_h + 2048, qkv_l + 2048,
                                                     vt_h, vt_l, 3072, M_ROWS);

    // attention: 256 blocks (1/CU), 512 threads, QBLK=256, double-buffered K/V
    k_attn<<<256, 512, 0, stream>>>(qkv_h, qkv_l, vt_h, vt_l, at_h, at_l);

    // Wo: BM=64 -> 512 blocks
    k_gemm<2, 0><<<512, 256, 0, stream>>>(at_h, at_l, woT_h, woT_l, bo, nullptr, nullptr,
                                          out, nullptr, nullptr, M_ROWS, 1024, 1024, 8);
}

// Round 6
// 314.976 us; speedup vs baseline: 1.3646x; 1.0508x over previous
//
#include <hip/hip_runtime.h>
#include <hip/hip_bf16.h>
#include <math.h>

#define D_MODEL 1024
#define ATT 1024
#define NHEAD 16
#define HDIM 64
#define BATCH 2
#define SEQ 2048
#define M_ROWS (BATCH * SEQ) /* 4096 */

typedef unsigned short u16;
typedef unsigned int u32;
typedef __bf16 bf16x8 __attribute__((ext_vector_type(8)));
typedef float f4 __attribute__((ext_vector_type(4)));
typedef u16 u16x8 __attribute__((ext_vector_type(8)));
typedef u16 u16x4 __attribute__((ext_vector_type(4)));

static_assert(sizeof(u16x8) == 16, "u16x8 must be 16B");

// ---------- bf16 split helpers ----------
__device__ __forceinline__ u16 f32_to_bf16(float f) {
    union { float f; unsigned u; } c; c.f = f;
    unsigned u = c.u;
    return (u16)((u + 0x7FFFu + ((u >> 16) & 1u)) >> 16);  // RNE
}
__device__ __forceinline__ float bf16_to_f32(u16 h) {
    union { unsigned u; float f; } c; c.u = ((unsigned)h) << 16;
    return c.f;
}
__device__ __forceinline__ void split2(float f, u16& hi, u16& lo) {
    hi = f32_to_bf16(f);
    lo = f32_to_bf16(f - bf16_to_f32(hi));
}

__device__ __forceinline__ f4 mfma16(u16x8 a, u16x8 b, f4 c) {
    union U { u16x8 u; bf16x8 b; };
    U ua, ub; ua.u = a; ub.u = b;
    return __builtin_amdgcn_mfma_f32_16x16x32_bf16(ua.b, ub.b, c, 0, 0, 0);
}

// async global->LDS, 16B per lane, dest = uniform base + lane*16
__device__ __forceinline__ void gload16(const void* g, void* l) {
    __builtin_amdgcn_global_load_lds(
        (const __attribute__((address_space(1))) void*)g,
        (__attribute__((address_space(3))) void*)l, 16, 0, 0);
}

template <int N>
__device__ __forceinline__ void waitcnt_vm() {
    if constexpr (N == 0)      asm volatile("s_waitcnt vmcnt(0)" ::: "memory");
    else if constexpr (N == 4) asm volatile("s_waitcnt vmcnt(4)" ::: "memory");
    else if constexpr (N == 6) asm volatile("s_waitcnt vmcnt(6)" ::: "memory");
    else if constexpr (N == 8) asm volatile("s_waitcnt vmcnt(8)" ::: "memory");
}
#define BARRIER() __builtin_amdgcn_s_barrier()

// ---------- kernel 1: elementwise split of x ----------
__global__ __launch_bounds__(256) void k_split(const float* __restrict__ in,
                                               u16* __restrict__ hi,
                                               u16* __restrict__ lo, int n4) {
    int i = blockIdx.x * blockDim.x + threadIdx.x;
    if (i >= n4) return;
    const float4 v = ((const float4*)in)[i];
    float vv[4] = {v.x, v.y, v.z, v.w};
    u16 hh[4], ll[4];
#pragma unroll
    for (int j = 0; j < 4; ++j) split2(vv[j], hh[j], ll[j]);
    u16x4 hv = {hh[0], hh[1], hh[2], hh[3]};
    u16x4 lv = {ll[0], ll[1], ll[2], ll[3]};
    *(u16x4*)(hi + (size_t)i * 4) = hv;
    *(u16x4*)(lo + (size_t)i * 4) = lv;
}

// ---------- kernel 2: split + transpose a 1024x1024 weight ----------
__global__ __launch_bounds__(256) void k_splitT(const float* __restrict__ W,
                                                u16* __restrict__ hiT,
                                                u16* __restrict__ loT) {
    __shared__ float tile[32][33];
    int n0 = blockIdx.x * 32, k0 = blockIdx.y * 32;
    int tx = threadIdx.x, ty = threadIdx.y;  // (32,8)
#pragma unroll
    for (int j = 0; j < 4; ++j) {
        int r = ty + j * 8;
        tile[r][tx] = W[(size_t)(k0 + r) * ATT + n0 + tx];
    }
    __syncthreads();
#pragma unroll
    for (int j = 0; j < 4; ++j) {
        int r = ty + j * 8;              // local n
        float v = tile[tx][r];           // = W[k0+tx][n0+r]
        u16 h, l; split2(v, h, l);
        hiT[(size_t)(n0 + r) * D_MODEL + k0 + tx] = h;
        loT[(size_t)(n0 + r) * D_MODEL + k0 + tx] = l;
    }
}

// ---------- kernel 2b: u16 tiled transpose (for V^T), z selects hi/lo ----------
__global__ __launch_bounds__(256) void k_transpose(
    const u16* __restrict__ src_h, const u16* __restrict__ src_l,
    u16* __restrict__ dst_h, u16* __restrict__ dst_l, int srcld, int dstld) {
    __shared__ u16 t[64][72];
    const u16* src = blockIdx.z ? src_l : src_h;
    u16* dst = blockIdx.z ? dst_l : dst_h;
    int n0 = blockIdx.x * 64, m0 = blockIdx.y * 64;
    int tid = threadIdx.x;
    int r = tid >> 2, c16 = (tid & 3) * 16;
    *(u16x8*)&t[r][c16]     = *(const u16x8*)&src[(size_t)(m0 + r) * srcld + n0 + c16];
    *(u16x8*)&t[r][c16 + 8] = *(const u16x8*)&src[(size_t)(m0 + r) * srcld + n0 + c16 + 8];
    __syncthreads();
    u16x8 o0, o1;
#pragma unroll
    for (int j = 0; j < 8; ++j) { o0[j] = t[c16 + j][r]; o1[j] = t[c16 + 8 + j][r]; }
    *(u16x8*)&dst[(size_t)(n0 + r) * dstld + m0 + c16]     = o0;
    *(u16x8*)&dst[(size_t)(n0 + r) * dstld + m0 + c16 + 8] = o1;
}

// ---------- kernel 3: split-bf16 GEMM, double-buffered LDS + counted vmcnt ----------
// C[M][N] = A[M][K] * B^T[N][K] + bias.  BM = MF*32, BN = 128, BK = 32.
// swizzle: 16B block cb' = cb ^ ((row>>1)&3) (pre-swizzled source + swizzled read).
// SPLIT_OUT==1: lo-part stored only for cols < 1024 (only Q's lo is consumed).
template <int MF, int SPLIT_OUT>
__global__ __launch_bounds__(256) void k_gemm(
    const u16* __restrict__ Ah, const u16* __restrict__ Al,
    const u16* __restrict__ Bh, const u16* __restrict__ Bl,
    const float* __restrict__ bq, const float* __restrict__ bk,
    const float* __restrict__ bv,
    float* __restrict__ Co, u16* __restrict__ Ch, u16* __restrict__ Cl,
    int M, int N, int K, int NBX) {
    constexpr int BM = MF * 32;
    constexpr int SAe = BM * 32;               // u16 elems per A buffer
    constexpr int NCH = (2 * BM + 256) / 16;   // 1KB chunks per K-step
    constexpr int CPW = NCH / 4;               // chunks per wave (8 or 6)
    constexpr int BUFE = (2 * BM + 256) * 32;  // u16 elems per K-step buffer
    __shared__ u16 sh[2 * BUFE];

    int tid = threadIdx.x;
    int wave = tid >> 6, lane = tid & 63, lg = lane >> 4, ln = lane & 15;
    int wm = wave >> 1, wn = wave & 1;

    int nb = gridDim.x;
    int bs = (blockIdx.x & 7) * (nb >> 3) + (blockIdx.x >> 3);  // XCD-chunked
    int bx = bs % NBX, by = bs / NBX;
    int m0 = by * BM, n0 = bx * 128;

    f4 acc[MF][4];
#pragma unroll
    for (int i = 0; i < MF; ++i)
#pragma unroll
        for (int j = 0; j < 4; ++j) acc[i][j] = f4{0.f, 0.f, 0.f, 0.f};

    // hoisted staging source pointers (advance by 32 elems per K-step)
    const u16* gp[CPW];
#pragma unroll
    for (int j = 0; j < CPW; ++j) {
        int c = wave * CPW + j;
        int bo = c << 10;  // byte offset within a K-step buffer (wave-uniform)
        const u16* base; int local, r0;
        if (bo < BM * 64)                { base = Ah; local = bo;                 r0 = m0; }
        else if (bo < 2 * BM * 64)       { base = Al; local = bo - BM * 64;       r0 = m0; }
        else if (bo < 2 * BM * 64 + 8192){ base = Bh; local = bo - 2 * BM * 64;   r0 = n0; }
        else                             { base = Bl; local = bo - 2 * BM * 64 - 8192; r0 = n0; }
        int lo2 = local + lane * 16;
        int row = lo2 >> 6;
        int cb  = (lo2 >> 4) & 3;
        int cbs = cb ^ ((row >> 1) & 3);      // inverse-swizzled SOURCE
        gp[j] = base + (size_t)(r0 + row) * K + cbs * 8;
    }

    // hoisted fragment read offsets (loop-invariant)
    int offA[MF], offB[4];
#pragma unroll
    for (int mf = 0; mf < MF; ++mf) {
        int row = wm * (MF * 16) + mf * 16 + ln;
        offA[mf] = row * 32 + ((lg ^ ((row >> 1) & 3)) << 3);
    }
#pragma unroll
    for (int nf = 0; nf < 4; ++nf) {
        int row = wn * 64 + nf * 16 + ln;
        offB[nf] = row * 32 + ((lg ^ ((row >> 1) & 3)) << 3);
    }

    auto stage = [&](int bsel) {
#pragma unroll
        for (int j = 0; j < CPW; ++j)
            gload16(gp[j], (char*)sh + bsel * (BUFE * 2) + ((wave * CPW + j) << 10));
    };
    auto adv = [&]() {
#pragma unroll
        for (int j = 0; j < CPW; ++j) gp[j] += 32;
    };
    auto compute = [&](int sb) {  // sb = u16 index base of buffer
        u16x8 a_h[MF], a_l[MF], b_h[4], b_l[4];
#pragma unroll
        for (int mf = 0; mf < MF; ++mf) {
            a_h[mf] = *(const u16x8*)&sh[sb + offA[mf]];
            a_l[mf] = *(const u16x8*)&sh[sb + SAe + offA[mf]];
        }
#pragma unroll
        for (int nf = 0; nf < 4; ++nf) {
            b_h[nf] = *(const u16x8*)&sh[sb + 2 * SAe + offB[nf]];
            b_l[nf] = *(const u16x8*)&sh[sb + 2 * SAe + 4096 + offB[nf]];
        }
#pragma unroll
        for (int mf = 0; mf < MF; ++mf)
#pragma unroll
            for (int nf = 0; nf < 4; ++nf) {
                acc[mf][nf] = mfma16(a_h[mf], b_h[nf], acc[mf][nf]);
                acc[mf][nf] = mfma16(a_h[mf], b_l[nf], acc[mf][nf]);
                acc[mf][nf] = mfma16(a_l[mf], b_h[nf], acc[mf][nf]);
            }
    };

    // ---- pipelined K loop: K/32 steps (must be even), 2 buffers ----
    const int NS = K / 32;
    stage(0); adv();
    for (int t = 0; t < NS - 2; t += 2) {
        stage(1); adv();
        waitcnt_vm<CPW>(); BARRIER();
        compute(0);
        BARRIER();
        stage(0); adv();
        waitcnt_vm<CPW>(); BARRIER();
        compute(BUFE);
        BARRIER();
    }
    stage(1);
    waitcnt_vm<CPW>(); BARRIER();
    compute(0);
    BARRIER();
    waitcnt_vm<0>(); BARRIER();
    compute(BUFE);

#pragma unroll
    for (int mf = 0; mf < MF; ++mf)
#pragma unroll
        for (int nf = 0; nf < 4; ++nf) {
            int col = n0 + wn * 64 + nf * 16 + ln;
            float bb;
            if (bk) bb = col < 1024 ? bq[col] : (col < 2048 ? bk[col - 1024] : bv[col - 2048]);
            else    bb = bq[col];
#pragma unroll
            for (int r = 0; r < 4; ++r) {
                int row = m0 + wm * (MF * 16) + mf * 16 + lg * 4 + r;
                float v = acc[mf][nf][r] + bb;
                if (SPLIT_OUT) {
                    u16 h, l; split2(v, h, l);
                    Ch[(size_t)row * N + col] = h;
                    if (col < 1024) Cl[(size_t)row * N + col] = l;  // only Q-lo consumed
                } else {
                    Co[(size_t)row * N + col] = v;
                }
            }
        }
}

// ---------- kernel 4: flash attention, QBLK=128, bf16 K/V, double-buffered ----
// Q split (hi/lo in regs); K,V plain bf16 (hi only).
// LDS (u16): buf0 [0,8192): Kh[0,4096) Vh[4096,8192); buf1 [8192,16384);
// P [16384,24576) = 48KB total. 128B rows, swizzle kb' = kb ^ (row&7).
#define ATTN_SCALE 0.18033688f  /* 0.125 * log2(e) */

__global__ __launch_bounds__(256) void k_attn(
    const u16* __restrict__ qkv_h, const u16* __restrict__ qkv_l,
    const u16* __restrict__ vt,
    u16* __restrict__ Oh, u16* __restrict__ Ol) {
    __shared__ u16 sh[24576];
    int tid = threadIdx.x;
    int w = tid >> 6, lane = tid & 63, lg = lane >> 4, ln = lane & 15;

    int bs = (blockIdx.x & 7) * 64 + (blockIdx.x >> 3);  // XCD-chunked, 512 blocks
    int qt = bs & 15, h = (bs >> 4) & 15, b = bs >> 8;
    int q0 = qt * 128;

    // Q fragments in registers (wave owns 32 q-rows)
    u16x8 qh[2][2], ql[2][2];
#pragma unroll
    for (int mf = 0; mf < 2; ++mf) {
        int row = q0 + w * 32 + mf * 16 + ln;
        const u16* ph_ = qkv_h + (size_t)(b * SEQ + row) * 3072 + h * HDIM;
        const u16* pl_ = qkv_l + (size_t)(b * SEQ + row) * 3072 + h * HDIM;
#pragma unroll
        for (int ks = 0; ks < 2; ++ks) {
            qh[mf][ks] = *(const u16x8*)(ph_ + ks * 32 + lg * 8);
            ql[mf][ks] = *(const u16x8*)(pl_ + ks * 32 + lg * 8);
        }
    }

    f4 acco[2][4], accl[2];
#pragma unroll
    for (int i = 0; i < 2; ++i) {
#pragma unroll
        for (int j = 0; j < 4; ++j) acco[i][j] = f4{0.f, 0.f, 0.f, 0.f};
        accl[i] = f4{0.f, 0.f, 0.f, 0.f};
    }
    float run_m[2][4];
#pragma unroll
    for (int i = 0; i < 2; ++i)
#pragma unroll
        for (int r = 0; r < 4; ++r) run_m[i][r] = -INFINITY;

    u16x8 ones;
#pragma unroll
    for (int j = 0; j < 8; ++j) ones[j] = 0x3F80;  // bf16 1.0

    // staging: wave w stages {bt = w>>1: 0=K, 1=V} half {hf = w&1}: 4 chunks of 1KB
    int bt = w >> 1, hf = w & 1;
    const u16* gp[4];
    {
        int r0 = hf * 32 + (lane >> 3);
        int kbs = (lane & 7) ^ (lane >> 3);
        if (bt == 0) {
            const u16* base = qkv_h + (size_t)(b * SEQ) * 3072 + 1024 + h * HDIM;
#pragma unroll
            for (int j = 0; j < 4; ++j)
                gp[j] = base + (size_t)(r0 + j * 8) * 3072 + kbs * 8;
        } else {
            const u16* base = vt + (size_t)(h * HDIM) * M_ROWS + b * SEQ;
#pragma unroll
            for (int j = 0; j < 4; ++j)
                gp[j] = base + (size_t)(r0 + j * 8) * M_ROWS + kbs * 8;
        }
    }
    const int gstride = (bt == 0) ? 64 * 3072 : 64;
    const int cb0 = (w * 4) << 10;  // byte base of wave's chunks within a buffer

    auto stage = [&](int bsel) {
#pragma unroll
        for (int j = 0; j < 4; ++j)
            gload16(gp[j], (char*)sh + cb0 + (j << 10) + bsel * 16384);
    };
    auto adv = [&]() {
#pragma unroll
        for (int j = 0; j < 4; ++j) gp[j] += gstride;
    };

    // hoisted ds_read offsets (u16 indices, relative to buffer base)
    int offQK[4][2], offPr[2][2];
#pragma unroll
    for (int nf = 0; nf < 4; ++nf) {
        int krow = nf * 16 + ln;
#pragma unroll
        for (int ks = 0; ks < 2; ++ks)
            offQK[nf][ks] = krow * 64 + (((4 * ks + lg) ^ (krow & 7)) << 3);
    }
#pragma unroll
    for (int mf = 0; mf < 2; ++mf) {
        int prow = w * 32 + mf * 16 + ln;
#pragma unroll
        for (int ks = 0; ks < 2; ++ks)
            offPr[mf][ks] = 16384 + prow * 64 + (((4 * ks + lg) ^ (prow & 7)) << 3);
    }

    auto compute = [&](int base) {  // base = u16 index of KV buffer
        f4 s[2][4];
#pragma unroll
        for (int i = 0; i < 2; ++i)
#pragma unroll
            for (int j = 0; j < 4; ++j) s[i][j] = f4{0.f, 0.f, 0.f, 0.f};
#pragma unroll
        for (int nf = 0; nf < 4; ++nf) {
#pragma unroll
            for (int ks = 0; ks < 2; ++ks) {
                u16x8 bh = *(const u16x8*)&sh[base + offQK[nf][ks]];
#pragma unroll
                for (int mf = 0; mf < 2; ++mf) {
                    s[mf][nf] = mfma16(qh[mf][ks], bh, s[mf][nf]);
                    s[mf][nf] = mfma16(ql[mf][ks], bh, s[mf][nf]);
                }
            }
        }
#pragma unroll
        for (int mf = 0; mf < 2; ++mf) {
#pragma unroll
            for (int r = 0; r < 4; ++r) {
                float mx = fmaxf(fmaxf(s[mf][0][r], s[mf][1][r]),
                                 fmaxf(s[mf][2][r], s[mf][3][r]));
#pragma unroll
                for (int d = 1; d < 16; d <<= 1) mx = fmaxf(mx, __shfl_xor(mx, d));
                float mx2 = mx * ATTN_SCALE;
                bool need = mx2 > run_m[mf][r] + 11.0f;
                float nm = need ? mx2 : run_m[mf][r];
                int qrow = w * 32 + mf * 16 + lg * 4 + r;
                int swz = qrow & 7;
                int pbase = 16384 + qrow * 64 + (ln & 7);
#pragma unroll
                for (int nf = 0; nf < 4; ++nf) {
                    float p = __builtin_amdgcn_exp2f(s[mf][nf][r] * ATTN_SCALE - nm);
                    sh[pbase + (((nf * 2 + (ln >> 3)) ^ swz) << 3)] = f32_to_bf16(p);
                }
                if (__any((int)need)) {
                    float corr = __builtin_amdgcn_exp2f(run_m[mf][r] - nm);
#pragma unroll
                    for (int nf = 0; nf < 4; ++nf) acco[mf][nf][r] *= corr;
                    accl[mf][r] *= corr;
                    run_m[mf][r] = nm;
                }
            }
        }
        // P wave-private: no barrier
#pragma unroll
        for (int ks = 0; ks < 2; ++ks) {
            u16x8 pa[2];
#pragma unroll
            for (int mf = 0; mf < 2; ++mf)
                pa[mf] = *(const u16x8*)&sh[offPr[mf][ks]];
#pragma unroll
            for (int nf = 0; nf < 4; ++nf) {
                u16x8 vh = *(const u16x8*)&sh[base + 4096 + offQK[nf][ks]];
#pragma unroll
                for (int mf = 0; mf < 2; ++mf)
                    acco[mf][nf] = mfma16(pa[mf], vh, acco[mf][nf]);
            }
            accl[0] = mfma16(pa[0], ones, accl[0]);
            accl[1] = mfma16(pa[1], ones, accl[1]);
        }
    };

    // ---- pipelined K/V loop: 32 tiles, 2 buffers ----
    stage(0); adv();
    for (int t = 0; t < 30; t += 2) {
        stage(1); adv();
        waitcnt_vm<4>(); BARRIER();
        compute(0);
        BARRIER();
        stage(0); adv();
        waitcnt_vm<4>(); BARRIER();
        compute(8192);
        BARRIER();
    }
    stage(1);
    waitcnt_vm<4>(); BARRIER();
    compute(0);
    BARRIER();
    waitcnt_vm<0>(); BARRIER();
    compute(8192);

    // ---- epilogue: O /= l, split-write ----
#pragma unroll
    for (int mf = 0; mf < 2; ++mf)
#pragma unroll
        for (int nf = 0; nf < 4; ++nf) {
            int col = h * HDIM + nf * 16 + ln;
#pragma unroll
            for (int r = 0; r < 4; ++r) {
                int row = q0 + w * 32 + mf * 16 + lg * 4 + r;
                float v = acco[mf][nf][r] / accl[mf][r];
                u16 hh, ll; split2(v, hh, ll);
                Oh[(size_t)(b * SEQ + row) * ATT + col] = hh;
                Ol[(size_t)(b * SEQ + row) * ATT + col] = ll;
            }
        }
}

// ---------- launcher ----------
extern "C" void kernel_launch(void* const* d_in, const int* in_sizes, int n_in,
                              void* d_out, int out_size, void* d_ws, size_t ws_size,
                              hipStream_t stream) {
    const float* x  = (const float*)d_in[0];
    const float* Wq = (const float*)d_in[1];
    const float* bq = (const float*)d_in[2];
    const float* Wk = (const float*)d_in[3];
    const float* bk = (const float*)d_in[4];
    const float* Wv = (const float*)d_in[5];
    const float* bv = (const float*)d_in[6];
    const float* Wo = (const float*)d_in[7];
    const float* bo = (const float*)d_in[8];
    float* out = (float*)d_out;

    const size_t MK = (size_t)M_ROWS * ATT;   // 4M elems
    const size_t WE = (size_t)D_MODEL * ATT;  // 1M elems
    const size_t M3 = (size_t)M_ROWS * 3072;  // fused qkv elems

    char* p = (char*)d_ws;
    auto alloc = [&](size_t bytes) -> u16* {
        u16* r = (u16*)p;
        p += (bytes + 255) & ~(size_t)255;
        return r;
    };
    u16* x_hi  = alloc(MK * 2); u16* x_lo  = alloc(MK * 2);
    u16* wT_h  = alloc(3 * WE * 2); u16* wT_l  = alloc(3 * WE * 2);  // [Wq;Wk;Wv]^T stacked
    u16* woT_h = alloc(WE * 2); u16* woT_l = alloc(WE * 2);
    u16* qkv_h = alloc(M3 * 2); u16* qkv_l = alloc(M3 * 2);          // [M][3072]
    u16* vt_h  = alloc(MK * 2); u16* vt_l  = alloc(MK * 2);          // V^T [1024][4096]
    u16* at_h = x_hi; u16* at_l = x_lo;  // attention out reuses x buffers

    k_split<<<dim3((unsigned)(MK / 4 / 256)), 256, 0, stream>>>(x, x_hi, x_lo, (int)(MK / 4));

    dim3 bt(32, 8), gt(32, 32);
    k_splitT<<<gt, bt, 0, stream>>>(Wq, wT_h, wT_l);
    k_splitT<<<gt, bt, 0, stream>>>(Wk, wT_h + WE, wT_l + WE);
    k_splitT<<<gt, bt, 0, stream>>>(Wv, wT_h + 2 * WE, wT_l + 2 * WE);
    k_splitT<<<gt, bt, 0, stream>>>(Wo, woT_h, woT_l);

    // fused QKV: [4096 x 3072] = x[4096x1024] @ [Wq|Wk|Wv], 768 blocks
    k_gemm<4, 1><<<768, 256, 0, stream>>>(x_hi, x_lo, wT_h, wT_l, bq, bk, bv,
                                          nullptr, qkv_h, qkv_l, M_ROWS, 3072, 1024, 24);

    // V^T (hi only): qkv cols [2048,3072) -> vt [1024][4096]
    k_transpose<<<dim3(16, 64, 1), 256, 0, stream>>>(qkv_h + 2048, qkv_l + 2048,
                                                     vt_h, vt_l, 3072, M_ROWS);

    // attention: 512 blocks (2/CU), 256 threads, QBLK=128, bf16 K/V
    k_attn<<<512, 256, 0, stream>>>(qkv_h, qkv_l, vt_h, at_h, at_l);

    // Wo: BM=64 -> 512 blocks
    k_gemm<2, 0><<<512, 256, 0, stream>>>(at_h, at_l, woT_h, woT_l, bo, nullptr, nullptr,
                                          out, nullptr, nullptr, M_ROWS, 1024, 1024, 8);
}

// Round 8
// 277.357 us; speedup vs baseline: 1.5497x; 1.1356x over previous
//
#include <hip/hip_runtime.h>
#include <hip/hip_bf16.h>
#include <math.h>

#define D_MODEL 1024
#define ATT 1024
#define NHEAD 16
#define HDIM 64
#define BATCH 2
#define SEQ 2048
#define M_ROWS (BATCH * SEQ) /* 4096 */

typedef unsigned short u16;
typedef unsigned int u32;
typedef __bf16 bf16x8 __attribute__((ext_vector_type(8)));
typedef _Float16 f16x8 __attribute__((ext_vector_type(8)));
typedef float f4 __attribute__((ext_vector_type(4)));
typedef u16 u16x8 __attribute__((ext_vector_type(8)));
typedef u16 u16x4 __attribute__((ext_vector_type(4)));

static_assert(sizeof(u16x8) == 16, "u16x8 must be 16B");

// ---------- bf16 split helpers ----------
__device__ __forceinline__ u16 f32_to_bf16(float f) {
    union { float f; unsigned u; } c; c.f = f;
    unsigned u = c.u;
    return (u16)((u + 0x7FFFu + ((u >> 16) & 1u)) >> 16);  // RNE
}
__device__ __forceinline__ float bf16_to_f32(u16 h) {
    union { unsigned u; float f; } c; c.u = ((unsigned)h) << 16;
    return c.f;
}
__device__ __forceinline__ void split2(float f, u16& hi, u16& lo) {
    hi = f32_to_bf16(f);
    lo = f32_to_bf16(f - bf16_to_f32(hi));
}
// f32 -> f16 bit pattern (HW RNE via v_cvt_f16_f32)
__device__ __forceinline__ u16 f32_to_f16bits(float f) {
    union { _Float16 h; u16 u; } c; c.h = (_Float16)f; return c.u;
}

__device__ __forceinline__ f4 mfma16(u16x8 a, u16x8 b, f4 c) {  // bf16 inputs
    union U { u16x8 u; bf16x8 b; };
    U ua, ub; ua.u = a; ub.u = b;
    return __builtin_amdgcn_mfma_f32_16x16x32_bf16(ua.b, ub.b, c, 0, 0, 0);
}
__device__ __forceinline__ f4 mfma16h(u16x8 a, u16x8 b, f4 c) {  // f16 inputs
    union U { u16x8 u; f16x8 h; };
    U ua, ub; ua.u = a; ub.u = b;
    return __builtin_amdgcn_mfma_f32_16x16x32_f16(ua.h, ub.h, c, 0, 0, 0);
}

// async global->LDS, 16B per lane, dest = uniform base + lane*16
__device__ __forceinline__ void gload16(const void* g, void* l) {
    __builtin_amdgcn_global_load_lds(
        (const __attribute__((address_space(1))) void*)g,
        (__attribute__((address_space(3))) void*)l, 16, 0, 0);
}

template <int N>
__device__ __forceinline__ void waitcnt_vm() {
    if constexpr (N == 0)      asm volatile("s_waitcnt vmcnt(0)" ::: "memory");
    else if constexpr (N == 4) asm volatile("s_waitcnt vmcnt(4)" ::: "memory");
    else if constexpr (N == 6) asm volatile("s_waitcnt vmcnt(6)" ::: "memory");
    else if constexpr (N == 8) asm volatile("s_waitcnt vmcnt(8)" ::: "memory");
}
#define BARRIER() __builtin_amdgcn_s_barrier()

// ---------- kernel 1: elementwise split of x ----------
__global__ __launch_bounds__(256) void k_split(const float* __restrict__ in,
                                               u16* __restrict__ hi,
                                               u16* __restrict__ lo, int n4) {
    int i = blockIdx.x * blockDim.x + threadIdx.x;
    if (i >= n4) return;
    const float4 v = ((const float4*)in)[i];
    float vv[4] = {v.x, v.y, v.z, v.w};
    u16 hh[4], ll[4];
#pragma unroll
    for (int j = 0; j < 4; ++j) split2(vv[j], hh[j], ll[j]);
    u16x4 hv = {hh[0], hh[1], hh[2], hh[3]};
    u16x4 lv = {ll[0], ll[1], ll[2], ll[3]};
    *(u16x4*)(hi + (size_t)i * 4) = hv;
    *(u16x4*)(lo + (size_t)i * 4) = lv;
}

// ---------- kernel 2: split + transpose a 1024x1024 weight ----------
__global__ __launch_bounds__(256) void k_splitT(const float* __restrict__ W,
                                                u16* __restrict__ hiT,
                                                u16* __restrict__ loT) {
    __shared__ float tile[32][33];
    int n0 = blockIdx.x * 32, k0 = blockIdx.y * 32;
    int tx = threadIdx.x, ty = threadIdx.y;  // (32,8)
#pragma unroll
    for (int j = 0; j < 4; ++j) {
        int r = ty + j * 8;
        tile[r][tx] = W[(size_t)(k0 + r) * ATT + n0 + tx];
    }
    __syncthreads();
#pragma unroll
    for (int j = 0; j < 4; ++j) {
        int r = ty + j * 8;              // local n
        float v = tile[tx][r];           // = W[k0+tx][n0+r]
        u16 h, l; split2(v, h, l);
        hiT[(size_t)(n0 + r) * D_MODEL + k0 + tx] = h;
        loT[(size_t)(n0 + r) * D_MODEL + k0 + tx] = l;
    }
}

// ---------- kernel 2b: u16 tiled transpose (for V^T) ----------
__global__ __launch_bounds__(256) void k_transpose(
    const u16* __restrict__ src, u16* __restrict__ dst, int srcld, int dstld) {
    __shared__ u16 t[64][72];
    int n0 = blockIdx.x * 64, m0 = blockIdx.y * 64;
    int tid = threadIdx.x;
    int r = tid >> 2, c16 = (tid & 3) * 16;
    *(u16x8*)&t[r][c16]     = *(const u16x8*)&src[(size_t)(m0 + r) * srcld + n0 + c16];
    *(u16x8*)&t[r][c16 + 8] = *(const u16x8*)&src[(size_t)(m0 + r) * srcld + n0 + c16 + 8];
    __syncthreads();
    u16x8 o0, o1;
#pragma unroll
    for (int j = 0; j < 8; ++j) { o0[j] = t[c16 + j][r]; o1[j] = t[c16 + 8 + j][r]; }
    *(u16x8*)&dst[(size_t)(n0 + r) * dstld + m0 + c16]     = o0;
    *(u16x8*)&dst[(size_t)(n0 + r) * dstld + m0 + c16 + 8] = o1;
}

// ---------- kernel 3: split-bf16 GEMM, double-buffered LDS + counted vmcnt ----------
// C[M][N] = A[M][K] * B^T[N][K] + bias.  BM = MF*32, BN = 128, BK = 32.
// swizzle: 16B block cb' = cb ^ ((row>>1)&3) (pre-swizzled source + swizzled read).
// SPLIT_OUT==1: f16 output (for attention internals).
template <int MF, int SPLIT_OUT>
__global__ __launch_bounds__(256) void k_gemm(
    const u16* __restrict__ Ah, const u16* __restrict__ Al,
    const u16* __restrict__ Bh, const u16* __restrict__ Bl,
    const float* __restrict__ bq, const float* __restrict__ bk,
    const float* __restrict__ bv,
    float* __restrict__ Co, u16* __restrict__ Ch,
    int M, int N, int K, int NBX) {
    constexpr int BM = MF * 32;
    constexpr int SAe = BM * 32;               // u16 elems per A buffer
    constexpr int NCH = (2 * BM + 256) / 16;   // 1KB chunks per K-step
    constexpr int CPW = NCH / 4;               // chunks per wave (8 or 6)
    constexpr int BUFE = (2 * BM + 256) * 32;  // u16 elems per K-step buffer
    __shared__ u16 sh[2 * BUFE];

    int tid = threadIdx.x;
    int wave = tid >> 6, lane = tid & 63, lg = lane >> 4, ln = lane & 15;
    int wm = wave >> 1, wn = wave & 1;

    int nb = gridDim.x;
    int bs = (blockIdx.x & 7) * (nb >> 3) + (blockIdx.x >> 3);  // XCD-chunked
    int bx = bs % NBX, by = bs / NBX;
    int m0 = by * BM, n0 = bx * 128;

    f4 acc[MF][4];
#pragma unroll
    for (int i = 0; i < MF; ++i)
#pragma unroll
        for (int j = 0; j < 4; ++j) acc[i][j] = f4{0.f, 0.f, 0.f, 0.f};

    // hoisted staging source pointers (advance by 32 elems per K-step)
    const u16* gp[CPW];
#pragma unroll
    for (int j = 0; j < CPW; ++j) {
        int c = wave * CPW + j;
        int bo = c << 10;  // byte offset within a K-step buffer (wave-uniform)
        const u16* base; int local, r0;
        if (bo < BM * 64)                { base = Ah; local = bo;                 r0 = m0; }
        else if (bo < 2 * BM * 64)       { base = Al; local = bo - BM * 64;       r0 = m0; }
        else if (bo < 2 * BM * 64 + 8192){ base = Bh; local = bo - 2 * BM * 64;   r0 = n0; }
        else                             { base = Bl; local = bo - 2 * BM * 64 - 8192; r0 = n0; }
        int lo2 = local + lane * 16;
        int row = lo2 >> 6;
        int cb  = (lo2 >> 4) & 3;
        int cbs = cb ^ ((row >> 1) & 3);      // inverse-swizzled SOURCE
        gp[j] = base + (size_t)(r0 + row) * K + cbs * 8;
    }

    // hoisted fragment read offsets (loop-invariant)
    int offA[MF], offB[4];
#pragma unroll
    for (int mf = 0; mf < MF; ++mf) {
        int row = wm * (MF * 16) + mf * 16 + ln;
        offA[mf] = row * 32 + ((lg ^ ((row >> 1) & 3)) << 3);
    }
#pragma unroll
    for (int nf = 0; nf < 4; ++nf) {
        int row = wn * 64 + nf * 16 + ln;
        offB[nf] = row * 32 + ((lg ^ ((row >> 1) & 3)) << 3);
    }

    auto stage = [&](int bsel) {
#pragma unroll
        for (int j = 0; j < CPW; ++j)
            gload16(gp[j], (char*)sh + bsel * (BUFE * 2) + ((wave * CPW + j) << 10));
    };
    auto adv = [&]() {
#pragma unroll
        for (int j = 0; j < CPW; ++j) gp[j] += 32;
    };
    auto compute = [&](int sb) {  // sb = u16 index base of buffer
        u16x8 a_h[MF], a_l[MF], b_h[4], b_l[4];
#pragma unroll
        for (int mf = 0; mf < MF; ++mf) {
            a_h[mf] = *(const u16x8*)&sh[sb + offA[mf]];
            a_l[mf] = *(const u16x8*)&sh[sb + SAe + offA[mf]];
        }
#pragma unroll
        for (int nf = 0; nf < 4; ++nf) {
            b_h[nf] = *(const u16x8*)&sh[sb + 2 * SAe + offB[nf]];
            b_l[nf] = *(const u16x8*)&sh[sb + 2 * SAe + 4096 + offB[nf]];
        }
#pragma unroll
        for (int mf = 0; mf < MF; ++mf)
#pragma unroll
            for (int nf = 0; nf < 4; ++nf) {
                acc[mf][nf] = mfma16(a_h[mf], b_h[nf], acc[mf][nf]);
                acc[mf][nf] = mfma16(a_h[mf], b_l[nf], acc[mf][nf]);
                acc[mf][nf] = mfma16(a_l[mf], b_h[nf], acc[mf][nf]);
            }
    };

    // ---- pipelined K loop: K/32 steps (must be even), 2 buffers ----
    const int NS = K / 32;
    stage(0); adv();
    for (int t = 0; t < NS - 2; t += 2) {
        stage(1); adv();
        waitcnt_vm<CPW>(); BARRIER();
        compute(0);
        BARRIER();
        stage(0); adv();
        waitcnt_vm<CPW>(); BARRIER();
        compute(BUFE);
        BARRIER();
    }
    stage(1);
    waitcnt_vm<CPW>(); BARRIER();
    compute(0);
    BARRIER();
    waitcnt_vm<0>(); BARRIER();
    compute(BUFE);

#pragma unroll
    for (int mf = 0; mf < MF; ++mf)
#pragma unroll
        for (int nf = 0; nf < 4; ++nf) {
            int col = n0 + wn * 64 + nf * 16 + ln;
            float bb;
            if (bk) bb = col < 1024 ? bq[col] : (col < 2048 ? bk[col - 1024] : bv[col - 2048]);
            else    bb = bq[col];
#pragma unroll
            for (int r = 0; r < 4; ++r) {
                int row = m0 + wm * (MF * 16) + mf * 16 + lg * 4 + r;
                float v = acc[mf][nf][r] + bb;
                if (SPLIT_OUT) {
                    Ch[(size_t)row * N + col] = f32_to_f16bits(v);
                } else {
                    Co[(size_t)row * N + col] = v;
                }
            }
        }
}

// ---------- kernel 4: flash attention, QBLK=128, f16 Q/K/V/P, double-buffered ----
// LDS (u16): buf0 [0,8192): K[0,4096) V[4096,8192); buf1 [8192,16384);
// P [16384,24576) = 48KB total. 128B rows, swizzle kb' = kb ^ (row&7).
#define ATTN_SCALE 0.18033688f  /* 0.125 * log2(e) */

__global__ __launch_bounds__(256) void k_attn(
    const u16* __restrict__ qkv, const u16* __restrict__ vt,
    u16* __restrict__ Oh, u16* __restrict__ Ol) {
    __shared__ u16 sh[24576];
    int tid = threadIdx.x;
    int w = tid >> 6, lane = tid & 63, lg = lane >> 4, ln = lane & 15;

    int bs = (blockIdx.x & 7) * 64 + (blockIdx.x >> 3);  // XCD-chunked, 512 blocks
    int qt = bs & 15, h = (bs >> 4) & 15, b = bs >> 8;
    int q0 = qt * 128;

    // Q fragments in registers (wave owns 32 q-rows), f16
    u16x8 qh[2][2];
#pragma unroll
    for (int mf = 0; mf < 2; ++mf) {
        int row = q0 + w * 32 + mf * 16 + ln;
        const u16* ph_ = qkv + (size_t)(b * SEQ + row) * 3072 + h * HDIM;
#pragma unroll
        for (int ks = 0; ks < 2; ++ks)
            qh[mf][ks] = *(const u16x8*)(ph_ + ks * 32 + lg * 8);
    }

    f4 acco[2][4], accl[2];
#pragma unroll
    for (int i = 0; i < 2; ++i) {
#pragma unroll
        for (int j = 0; j < 4; ++j) acco[i][j] = f4{0.f, 0.f, 0.f, 0.f};
        accl[i] = f4{0.f, 0.f, 0.f, 0.f};
    }
    float run_m[2][4];
#pragma unroll
    for (int i = 0; i < 2; ++i)
#pragma unroll
        for (int r = 0; r < 4; ++r) run_m[i][r] = -INFINITY;

    u16x8 ones;
#pragma unroll
    for (int j = 0; j < 8; ++j) ones[j] = 0x3C00;  // f16 1.0

    // staging: wave w stages {bt = w>>1: 0=K, 1=V} half {hf = w&1}: 4 chunks of 1KB
    int bt = w >> 1, hf = w & 1;
    const u16* gp[4];
    {
        int r0 = hf * 32 + (lane >> 3);
        int kbs = (lane & 7) ^ (lane >> 3);
        if (bt == 0) {
            const u16* base = qkv + (size_t)(b * SEQ) * 3072 + 1024 + h * HDIM;
#pragma unroll
            for (int j = 0; j < 4; ++j)
                gp[j] = base + (size_t)(r0 + j * 8) * 3072 + kbs * 8;
        } else {
            const u16* base = vt + (size_t)(h * HDIM) * M_ROWS + b * SEQ;
#pragma unroll
            for (int j = 0; j < 4; ++j)
                gp[j] = base + (size_t)(r0 + j * 8) * M_ROWS + kbs * 8;
        }
    }
    const int gstride = (bt == 0) ? 64 * 3072 : 64;
    const int cb0 = (w * 4) << 10;  // byte base of wave's chunks within a buffer

    auto stage = [&](int bsel) {
#pragma unroll
        for (int j = 0; j < 4; ++j)
            gload16(gp[j], (char*)sh + cb0 + (j << 10) + bsel * 16384);
    };
    auto adv = [&]() {
#pragma unroll
        for (int j = 0; j < 4; ++j) gp[j] += gstride;
    };

    // hoisted ds_read offsets (u16 indices, relative to buffer base)
    int offQK[4][2], offPr[2][2];
#pragma unroll
    for (int nf = 0; nf < 4; ++nf) {
        int krow = nf * 16 + ln;
#pragma unroll
        for (int ks = 0; ks < 2; ++ks)
            offQK[nf][ks] = krow * 64 + (((4 * ks + lg) ^ (krow & 7)) << 3);
    }
#pragma unroll
    for (int mf = 0; mf < 2; ++mf) {
        int prow = w * 32 + mf * 16 + ln;
#pragma unroll
        for (int ks = 0; ks < 2; ++ks)
            offPr[mf][ks] = 16384 + prow * 64 + (((4 * ks + lg) ^ (prow & 7)) << 3);
    }

    auto compute = [&](int base) {  // base = u16 index of KV buffer
        f4 s[2][4];
#pragma unroll
        for (int i = 0; i < 2; ++i)
#pragma unroll
            for (int j = 0; j < 4; ++j) s[i][j] = f4{0.f, 0.f, 0.f, 0.f};
#pragma unroll
        for (int nf = 0; nf < 4; ++nf) {
#pragma unroll
            for (int ks = 0; ks < 2; ++ks) {
                u16x8 bh = *(const u16x8*)&sh[base + offQK[nf][ks]];
#pragma unroll
                for (int mf = 0; mf < 2; ++mf)
                    s[mf][nf] = mfma16h(qh[mf][ks], bh, s[mf][nf]);
            }
        }
#pragma unroll
        for (int mf = 0; mf < 2; ++mf) {
#pragma unroll
            for (int r = 0; r < 4; ++r) {
                // defer-guard: skip reduce+rescale unless some key may exceed +11
                float lmx = fmaxf(fmaxf(s[mf][0][r], s[mf][1][r]),
                                  fmaxf(s[mf][2][r], s[mf][3][r]));
                bool maybe = lmx * ATTN_SCALE > run_m[mf][r] + 11.0f;
                if (__any((int)maybe)) {
                    float mx = lmx;
#pragma unroll
                    for (int d = 1; d < 16; d <<= 1) mx = fmaxf(mx, __shfl_xor(mx, d));
                    float nm = fmaxf(run_m[mf][r], mx * ATTN_SCALE);
                    float corr = __builtin_amdgcn_exp2f(run_m[mf][r] - nm);
#pragma unroll
                    for (int nf = 0; nf < 4; ++nf) acco[mf][nf][r] *= corr;
                    accl[mf][r] *= corr;
                    run_m[mf][r] = nm;
                }
                int qrow = w * 32 + mf * 16 + lg * 4 + r;
                int swz = qrow & 7;
                int pbase = 16384 + qrow * 64 + (ln & 7);
#pragma unroll
                for (int nf = 0; nf < 4; ++nf) {
                    float p = __builtin_amdgcn_exp2f(s[mf][nf][r] * ATTN_SCALE - run_m[mf][r]);
                    sh[pbase + (((nf * 2 + (ln >> 3)) ^ swz) << 3)] = f32_to_f16bits(p);
                }
            }
        }
        // P wave-private: no barrier
#pragma unroll
        for (int ks = 0; ks < 2; ++ks) {
            u16x8 pa[2];
#pragma unroll
            for (int mf = 0; mf < 2; ++mf)
                pa[mf] = *(const u16x8*)&sh[offPr[mf][ks]];
#pragma unroll
            for (int nf = 0; nf < 4; ++nf) {
                u16x8 vh = *(const u16x8*)&sh[base + 4096 + offQK[nf][ks]];
#pragma unroll
                for (int mf = 0; mf < 2; ++mf)
                    acco[mf][nf] = mfma16h(pa[mf], vh, acco[mf][nf]);
            }
            accl[0] = mfma16h(pa[0], ones, accl[0]);
            accl[1] = mfma16h(pa[1], ones, accl[1]);
        }
    };

    // ---- pipelined K/V loop: 32 tiles, 2 buffers ----
    stage(0); adv();
    for (int t = 0; t < 30; t += 2) {
        stage(1); adv();
        waitcnt_vm<4>(); BARRIER();
        compute(0);
        BARRIER();
        stage(0); adv();
        waitcnt_vm<4>(); BARRIER();
        compute(8192);
        BARRIER();
    }
    stage(1);
    waitcnt_vm<4>(); BARRIER();
    compute(0);
    BARRIER();
    waitcnt_vm<0>(); BARRIER();
    compute(8192);

    // ---- epilogue: O /= l, bf16-split write (feeds split-bf16 Wo GEMM) ----
#pragma unroll
    for (int mf = 0; mf < 2; ++mf)
#pragma unroll
        for (int nf = 0; nf < 4; ++nf) {
            int col = h * HDIM + nf * 16 + ln;
#pragma unroll
            for (int r = 0; r < 4; ++r) {
                int row = q0 + w * 32 + mf * 16 + lg * 4 + r;
                float v = acco[mf][nf][r] / accl[mf][r];
                u16 hh, ll; split2(v, hh, ll);
                Oh[(size_t)(b * SEQ + row) * ATT + col] = hh;
                Ol[(size_t)(b * SEQ + row) * ATT + col] = ll;
            }
        }
}

// ---------- launcher ----------
extern "C" void kernel_launch(void* const* d_in, const int* in_sizes, int n_in,
                              void* d_out, int out_size, void* d_ws, size_t ws_size,
                              hipStream_t stream) {
    const float* x  = (const float*)d_in[0];
    const float* Wq = (const float*)d_in[1];
    const float* bq = (const float*)d_in[2];
    const float* Wk = (const float*)d_in[3];
    const float* bk = (const float*)d_in[4];
    const float* Wv = (const float*)d_in[5];
    const float* bv = (const float*)d_in[6];
    const float* Wo = (const float*)d_in[7];
    const float* bo = (const float*)d_in[8];
    float* out = (float*)d_out;

    const size_t MK = (size_t)M_ROWS * ATT;   // 4M elems
    const size_t WE = (size_t)D_MODEL * ATT;  // 1M elems
    const size_t M3 = (size_t)M_ROWS * 3072;  // fused qkv elems

    char* p = (char*)d_ws;
    auto alloc = [&](size_t bytes) -> u16* {
        u16* r = (u16*)p;
        p += (bytes + 255) & ~(size_t)255;
        return r;
    };
    u16* x_hi  = alloc(MK * 2); u16* x_lo  = alloc(MK * 2);
    u16* wT_h  = alloc(3 * WE * 2); u16* wT_l  = alloc(3 * WE * 2);  // [Wq;Wk;Wv]^T stacked
    u16* woT_h = alloc(WE * 2); u16* woT_l = alloc(WE * 2);
    u16* qkv   = alloc(M3 * 2);                                      // [M][3072], f16
    u16* vt    = alloc(MK * 2);                                      // V^T [1024][4096], f16
    u16* at_h = x_hi; u16* at_l = x_lo;  // attention out reuses x buffers

    k_split<<<dim3((unsigned)(MK / 4 / 256)), 256, 0, stream>>>(x, x_hi, x_lo, (int)(MK / 4));

    dim3 bt(32, 8), gt(32, 32);
    k_splitT<<<gt, bt, 0, stream>>>(Wq, wT_h, wT_l);
    k_splitT<<<gt, bt, 0, stream>>>(Wk, wT_h + WE, wT_l + WE);
    k_splitT<<<gt, bt, 0, stream>>>(Wv, wT_h + 2 * WE, wT_l + 2 * WE);
    k_splitT<<<gt, bt, 0, stream>>>(Wo, woT_h, woT_l);

    // fused QKV: [4096 x 3072] = x[4096x1024] @ [Wq|Wk|Wv], 768 blocks, f16 out
    k_gemm<4, 1><<<768, 256, 0, stream>>>(x_hi, x_lo, wT_h, wT_l, bq, bk, bv,
                                          nullptr, qkv, M_ROWS, 3072, 1024, 24);

    // V^T (f16): qkv cols [2048,3072) -> vt [1024][4096]
    k_transpose<<<dim3(16, 64), 256, 0, stream>>>(qkv + 2048, vt, 3072, M_ROWS);

    // attention: 512 blocks (2/CU), 256 threads, QBLK=128, f16 internals
    k_attn<<<512, 256, 0, stream>>>(qkv, vt, at_h, at_l);

    // Wo: BM=64 -> 512 blocks, f32 out (split-bf16 inputs)
    k_gemm<2, 0><<<512, 256, 0, stream>>>(at_h, at_l, woT_h, woT_l, bo, nullptr, nullptr,
                                          out, nullptr, M_ROWS, 1024, 1024, 8);
}